// Round 8
// baseline (297.775 us; speedup 1.0000x reference)
//
#include <hip/hip_runtime.h>
#include <hip/hip_bf16.h>
#include <math.h>

#define B_SZ 1024
#define STOCH 1024
#define ACT 32
#define DETER 4096
#define TOKEN_DIM 512
#define HIDDEN 1024
#define NHEADS 8
#define HEADDIM 128
#define DSTATE 64
#define CONV_DIM 1152
#define IN_PROJ_DIM 2184
#define IPP2 2304         // in_proj N padded to 36*64
#define KIN 1088          // input GEMM K padded to 17*64
#define EPS 0.0001f

typedef float f32x4 __attribute__((ext_vector_type(4)));
typedef __bf16 bf16x8 __attribute__((ext_vector_type(8)));
typedef __bf16 bf16x4 __attribute__((ext_vector_type(4)));

__device__ __forceinline__ bf16x8 cvt8(float4 a, float4 b) {
    bf16x8 r;
    r[0] = (__bf16)a.x; r[1] = (__bf16)a.y; r[2] = (__bf16)a.z; r[3] = (__bf16)a.w;
    r[4] = (__bf16)b.x; r[5] = (__bf16)b.y; r[6] = (__bf16)b.z; r[7] = (__bf16)b.w;
    return r;
}

// ---------------- prep: in_proj_w -> bf16 (pad K to 1088) + input row build ----------------
#define N0C (512 * KIN / 4)
#define N3C (B_SZ * KIN / 4)
__global__ __launch_bounds__(256) void prep_small(
    const float* __restrict__ inproj,
    const float* __restrict__ stoch, const float* __restrict__ action,
    __bf16* __restrict__ w0, __bf16* __restrict__ inp)
{
    int i = blockIdx.x * 256 + threadIdx.x;
    bf16x4 o = { (__bf16)0.f, (__bf16)0.f, (__bf16)0.f, (__bf16)0.f };
    if (i < N0C) {
        int idx = i * 4;
        int rr = idx / KIN, cc = idx % KIN;
        if (cc < STOCH + ACT) {
            float4 v = *(const float4*)(inproj + (size_t)rr * (STOCH + ACT) + cc);
            o = bf16x4{ (__bf16)v.x, (__bf16)v.y, (__bf16)v.z, (__bf16)v.w };
        }
        ((bf16x4*)w0)[i] = o;
    } else if (i < N0C + N3C) {
        int j = i - N0C;
        int idx = j * 4;
        int b = idx / KIN, c = idx % KIN;
        if (c < STOCH) {
            float4 v = *(const float4*)(stoch + (size_t)b * STOCH + c);
            o = bf16x4{ (__bf16)v.x, (__bf16)v.y, (__bf16)v.z, (__bf16)v.w };
        } else if (c < STOCH + ACT) {
            float4 v = *(const float4*)(action + (size_t)b * ACT + (c - STOCH));
            float4 m;
            m.x = fabsf(v.x) > 1.f ? fabsf(v.x) : 1.f;
            m.y = fabsf(v.y) > 1.f ? fabsf(v.y) : 1.f;
            m.z = fabsf(v.z) > 1.f ? fabsf(v.z) : 1.f;
            m.w = fabsf(v.w) > 1.f ? fabsf(v.w) : 1.f;
            o = bf16x4{ (__bf16)(v.x / m.x), (__bf16)(v.y / m.y),
                        (__bf16)(v.z / m.z), (__bf16)(v.w / m.w) };
        }
        ((bf16x4*)inp)[j] = o;
    }
}

// ---------------- GEMM: 128x64 wg tile, wave 32x64, optional split-K, optional f32 W ------
// C = A_bf16(MxK) @ W(NrealxK)^T (rows >= Nreal zero)   M%128==0, N%64==0, K%64==0
template<bool SPLIT, bool WF32, typename OutT>
__global__ __launch_bounds__(256) void gemm_v2(
    const __bf16* __restrict__ A,
    const void* __restrict__ Wp,      // bf16 or f32 per WF32
    const float* __restrict__ bias,   // only used when !SPLIT (may be null)
    OutT* __restrict__ C,             // !SPLIT: MxN ; SPLIT: [z][M][N]
    int M, int N, int Nreal, int K, int chunk_steps)
{
    __shared__ __bf16 As[128 * 64];   // 128 rows x 128B, XOR-swizzled
    __shared__ __bf16 Ws[64 * 64];
    const int tid = threadIdx.x;
    const int bn = blockIdx.x * 64;
    const int bm = blockIdx.y * 128;
    const int nsteps = K >> 6;
    int s_begin = 0, s_end = nsteps;
    OutT* Cout = C;
    if (SPLIT) {
        int z = blockIdx.z;
        s_begin = z * chunk_steps;
        int se = s_begin + chunk_steps;
        s_end = se < nsteps ? se : nsteps;
        Cout = C + (size_t)z * M * N;
    }

    const int wid = tid >> 6;
    const int lane = tid & 63;
    const int wr = wid * 32;
    const int r = lane & 15;
    const int kb = (lane >> 4) * 16;

    const int row0 = tid >> 3;               // 0..31
    const int colb = (tid & 7) * 16;         // byte col in 128B bf16 row
    const int e0   = colb >> 1;              // element offset (8 elems per thread)
    const int wof = row0 * 128 + (colb ^ ((row0 & 7) << 4));
    char* Asb = (char*)As;
    char* Wsb = (char*)Ws;

    const __bf16* gA = A + (size_t)(bm + row0) * K + (s_begin << 6) + e0;
    const size_t aK32 = (size_t)32 * K;

    const int ar0 = wr + r;
    const int ar1 = wr + 16 + r;
    const int aswz = (ar0 & 7) << 4;
    const int bswz = (r & 7) << 4;

    f32x4 acc[2][4] = {};
    bf16x8 va0 = *(const bf16x8*)(gA);
    bf16x8 va1 = *(const bf16x8*)(gA + aK32);
    bf16x8 va2 = *(const bf16x8*)(gA + 2 * aK32);
    bf16x8 va3 = *(const bf16x8*)(gA + 3 * aK32);

    // W staging state
    const bool v0 = (bn + row0) < Nreal;
    const bool v1 = (bn + row0 + 32) < Nreal;
    bf16x8 vw0 = {}, vw1 = {};
    const __bf16* gW = nullptr;
    const float*  gWf0 = nullptr, *gWf1 = nullptr;
    if (WF32) {
        gWf0 = (const float*)Wp + (size_t)(bn + row0) * K + (s_begin << 6) + e0;
        gWf1 = gWf0 + (size_t)32 * K;
        float4 wa0{}, wb0{}, wa1{}, wb1{};
        if (v0) { wa0 = *(const float4*)gWf0; wb0 = *(const float4*)(gWf0 + 4); }
        if (v1) { wa1 = *(const float4*)gWf1; wb1 = *(const float4*)(gWf1 + 4); }
        vw0 = cvt8(wa0, wb0);
        vw1 = cvt8(wa1, wb1);
    } else {
        gW = (const __bf16*)Wp + (size_t)(bn + row0) * K + (s_begin << 6) + e0;
        if (v0) vw0 = *(const bf16x8*)(gW);
        if (v1) vw1 = *(const bf16x8*)(gW + aK32);
    }

    for (int s = s_begin; s < s_end; ++s) {
        __syncthreads();
        *(bf16x8*)(Asb + wof) = va0;
        *(bf16x8*)(Asb + wof + 32 * 128) = va1;
        *(bf16x8*)(Asb + wof + 64 * 128) = va2;
        *(bf16x8*)(Asb + wof + 96 * 128) = va3;
        *(bf16x8*)(Wsb + wof) = vw0;
        *(bf16x8*)(Wsb + wof + 32 * 128) = vw1;
        __syncthreads();
        if (s + 1 < s_end) {
            const int ko = (s + 1 - s_begin) << 6;
            va0 = *(const bf16x8*)(gA + ko);
            va1 = *(const bf16x8*)(gA + aK32 + ko);
            va2 = *(const bf16x8*)(gA + 2 * aK32 + ko);
            va3 = *(const bf16x8*)(gA + 3 * aK32 + ko);
            if (WF32) {
                float4 wa0{}, wb0{}, wa1{}, wb1{};
                if (v0) { wa0 = *(const float4*)(gWf0 + ko); wb0 = *(const float4*)(gWf0 + ko + 4); }
                if (v1) { wa1 = *(const float4*)(gWf1 + ko); wb1 = *(const float4*)(gWf1 + ko + 4); }
                vw0 = cvt8(wa0, wb0);
                vw1 = cvt8(wa1, wb1);
            } else {
                if (v0) vw0 = *(const bf16x8*)(gW + ko);
                if (v1) vw1 = *(const bf16x8*)(gW + aK32 + ko);
            }
        }
        #pragma unroll
        for (int ks = 0; ks < 2; ++ks) {
            const int cb = ks * 64 + kb;
            bf16x8 a0 = *(const bf16x8*)(Asb + ar0 * 128 + (cb ^ aswz));
            bf16x8 a1 = *(const bf16x8*)(Asb + ar1 * 128 + (cb ^ aswz));
            bf16x8 b0 = *(const bf16x8*)(Wsb + r * 128 + (cb ^ bswz));
            bf16x8 b1 = *(const bf16x8*)(Wsb + (r + 16) * 128 + (cb ^ bswz));
            bf16x8 b2 = *(const bf16x8*)(Wsb + (r + 32) * 128 + (cb ^ bswz));
            bf16x8 b3 = *(const bf16x8*)(Wsb + (r + 48) * 128 + (cb ^ bswz));
            acc[0][0] = __builtin_amdgcn_mfma_f32_16x16x32_bf16(a0, b0, acc[0][0], 0, 0, 0);
            acc[0][1] = __builtin_amdgcn_mfma_f32_16x16x32_bf16(a0, b1, acc[0][1], 0, 0, 0);
            acc[0][2] = __builtin_amdgcn_mfma_f32_16x16x32_bf16(a0, b2, acc[0][2], 0, 0, 0);
            acc[0][3] = __builtin_amdgcn_mfma_f32_16x16x32_bf16(a0, b3, acc[0][3], 0, 0, 0);
            acc[1][0] = __builtin_amdgcn_mfma_f32_16x16x32_bf16(a1, b0, acc[1][0], 0, 0, 0);
            acc[1][1] = __builtin_amdgcn_mfma_f32_16x16x32_bf16(a1, b1, acc[1][1], 0, 0, 0);
            acc[1][2] = __builtin_amdgcn_mfma_f32_16x16x32_bf16(a1, b2, acc[1][2], 0, 0, 0);
            acc[1][3] = __builtin_amdgcn_mfma_f32_16x16x32_bf16(a1, b3, acc[1][3], 0, 0, 0);
        }
    }

    const int cr = (lane >> 4) * 4;
    const int cc = lane & 15;
    #pragma unroll
    for (int mi = 0; mi < 2; mi++) {
        #pragma unroll
        for (int ni = 0; ni < 4; ni++) {
            int n = bn + ni * 16 + cc;
            #pragma unroll
            for (int j = 0; j < 4; j++) {
                int m = bm + wr + mi * 16 + cr + j;
                float v = acc[mi][ni][j];
                if (!SPLIT && bias) v += bias[n];
                Cout[(size_t)m * N + n] = (OutT)v;
            }
        }
    }
}

// ---------------- block-wide sum helper (256 threads) ----------------
__device__ __forceinline__ float block_sum(float v, float* red, int t) {
    #pragma unroll
    for (int off = 32; off >= 1; off >>= 1) v += __shfl_xor(v, off);
    if ((t & 63) == 0) red[t >> 6] = v;
    __syncthreads();
    float tot = red[0] + red[1] + red[2] + red[3];
    __syncthreads();
    return tot;
}

// ---------------- reduce_in: X = silu(rmsnorm(ΣP+bias, inw)); Hb = bf16(rmsnorm(X, nw)) ----
__global__ __launch_bounds__(256) void reduce_in_kernel(
    const float* __restrict__ P,      // [2][B][512]
    const float* __restrict__ bias,
    const float* __restrict__ inw,
    const float* __restrict__ nw,
    float* __restrict__ X, __bf16* __restrict__ Hb)
{
    __shared__ float red[4];
    int b = blockIdx.x, t = threadIdx.x;
    const size_t stride = (size_t)B_SZ * TOKEN_DIM;
    float h[2];
    float ss = 0.f;
    #pragma unroll
    for (int i = 0; i < 2; i++) {
        int c = t + i * 256;
        size_t o = (size_t)b * TOKEN_DIM + c;
        float v = P[o] + P[o + stride] + bias[c];
        h[i] = v;
        ss += v * v;
    }
    float tot = block_sum(ss, red, t);
    float sc = rsqrtf(tot / (float)TOKEN_DIM + EPS);
    float ss2 = 0.f;
    #pragma unroll
    for (int i = 0; i < 2; i++) {
        int c = t + i * 256;
        float v = h[i] * sc * inw[c];
        v = v / (1.f + expf(-v));        // silu
        h[i] = v;
        X[(size_t)b * TOKEN_DIM + c] = v;
        ss2 += v * v;
    }
    float tot2 = block_sum(ss2, red, t);
    float sc2 = rsqrtf(tot2 / (float)TOKEN_DIM + EPS);
    #pragma unroll
    for (int i = 0; i < 2; i++) {
        int c = t + i * 256;
        Hb[(size_t)b * TOKEN_DIM + c] = (__bf16)(h[i] * sc2 * nw[c]);
    }
}

// ---------------- reduce_out: newX = X + ΣP + ob; MODE0: X,Hb=rms(newX,w); MODE1: final tape ----
template<int MODE>
__global__ __launch_bounds__(256) void reduce_out_kernel(
    const float* __restrict__ P,      // [2][B][512]
    const float* __restrict__ ob,
    const float* __restrict__ Xin,
    const float* __restrict__ w,
    float* __restrict__ X,
    __bf16* __restrict__ Hb,
    const float* __restrict__ deter,
    float* __restrict__ out)
{
    __shared__ float red[4];
    int b = blockIdx.x, t = threadIdx.x;
    const size_t stride = (size_t)B_SZ * TOKEN_DIM;
    float h[2];
    float ss = 0.f;
    #pragma unroll
    for (int i = 0; i < 2; i++) {
        int c = t + i * 256;
        size_t o = (size_t)b * TOKEN_DIM + c;
        float v = Xin[o] + P[o] + P[o + stride] + ob[c];
        h[i] = v;
        ss += v * v;
    }
    float tot = block_sum(ss, red, t);
    float sc = rsqrtf(tot / (float)TOKEN_DIM + EPS);
    if (MODE == 0) {
        #pragma unroll
        for (int i = 0; i < 2; i++) {
            int c = t + i * 256;
            size_t o = (size_t)b * TOKEN_DIM + c;
            X[o] = h[i];
            Hb[o] = (__bf16)(h[i] * sc * w[c]);
        }
    } else {
        #pragma unroll
        for (int i = 0; i < 2; i++) {
            int c = t + i * 256;
            out[(size_t)b * DETER + 3584 + c] = h[i] * sc * w[c];
        }
        const float4* src = (const float4*)(deter + (size_t)b * DETER + TOKEN_DIM);
        float4* dst = (float4*)(out + (size_t)b * DETER);
        #pragma unroll
        for (int j = 0; j < 4; ++j) {
            int idx = t + j * 256;
            if (idx < 896) dst[idx] = src[idx];
        }
    }
}

// ---------------- fused conv + ssm + gate-rmsnorm (one block per batch row) ----------------
__global__ __launch_bounds__(256, 4) void conv_ssm_gate_kernel(
    const float* __restrict__ cs,      // B x CONV_DIM x 3
    const __bf16* __restrict__ proj,   // B x IPP2 (bf16)
    const float* __restrict__ cw,      // CONV_DIM x 4
    const float* __restrict__ cb,      // CONV_DIM
    const float* __restrict__ dtb,     // NHEADS
    const float* __restrict__ alog,    // NHEADS
    const float* __restrict__ Dv,      // NHEADS
    const float* __restrict__ pw,      // HIDDEN
    const float* __restrict__ ss,      // B x NHEADS x HEADDIM x DSTATE
    float* __restrict__ new_cs,
    float* __restrict__ new_ss,
    __bf16* __restrict__ Gb)           // B x HIDDEN
{
    __shared__ float convs[CONV_DIM];  // x(1024) | B(64) | C(64)
    __shared__ float yrow[HIDDEN];
    __shared__ float dts[NHEADS], dAs[NHEADS], dvs[NHEADS];
    __shared__ float red[4];

    int b = blockIdx.x, t = threadIdx.x;
    const __bf16* prow = proj + (size_t)b * IPP2;

    const int p0 = t >> 4;            // 0..15
    const int nq = (t & 15) * 4;      // 0..60
    const float* basep = ss + (size_t)b * NHEADS * HEADDIM * DSTATE;
    float* baseo = new_ss + (size_t)b * NHEADS * HEADDIM * DSTATE;

    // prefetch head 0 state (in flight during conv phase)
    f32x4 cur[8], nxt[8];
    #pragma unroll
    for (int it = 0; it < 8; ++it) {
        int p = it * 16 + p0;
        cur[it] = __builtin_nontemporal_load((const f32x4*)(basep + (size_t)p * DSTATE + nq));
    }

    if (t < NHEADS) {
        float dtr = (float)prow[HIDDEN + CONV_DIM + t] + dtb[t];
        float dt = dtr > 20.f ? dtr : log1pf(expf(dtr));
        dts[t] = dt;
        dAs[t] = expf(dt * -expf(alog[t]));
        dvs[t] = Dv[t];
    }
    // conv over 1152 channels
    for (int c = t; c < CONV_DIM; c += 256) {
        const float* s = cs + ((size_t)b * CONV_DIM + c) * 3;
        float s0 = s[0], s1 = s[1], s2 = s[2];
        float xbc = (float)prow[HIDDEN + c];
        float4 wv = *(const float4*)(cw + c * 4);
        float v = wv.x * s0 + wv.y * s1 + wv.z * s2 + wv.w * xbc + cb[c];
        v = v / (1.f + expf(-v));
        convs[c] = v;
        float* nc = new_cs + ((size_t)b * CONV_DIM + c) * 3;
        nc[0] = s1; nc[1] = s2; nc[2] = xbc;
    }
    __syncthreads();

    const f32x4 Bv = *(const f32x4*)&convs[HIDDEN + nq];
    const f32x4 Cv = *(const f32x4*)&convs[HIDDEN + DSTATE + nq];

    #pragma unroll
    for (int h = 0; h < NHEADS; ++h) {
        if (h + 1 < NHEADS) {
            #pragma unroll
            for (int it = 0; it < 8; ++it) {
                int p = it * 16 + p0;
                nxt[it] = __builtin_nontemporal_load(
                    (const f32x4*)(basep + (size_t)((h + 1) * HEADDIM + p) * DSTATE + nq));
            }
        }
        const float dt = dts[h], dA = dAs[h], Dk = dvs[h];
        float* op = baseo + (size_t)h * HEADDIM * DSTATE;
        #pragma unroll
        for (int it = 0; it < 8; ++it) {
            int p = it * 16 + p0;
            float xp = convs[h * HEADDIM + p];
            float dtx = dt * xp;
            f32x4 o = cur[it] * dA + dtx * Bv;
            __builtin_nontemporal_store(o, (f32x4*)(op + (size_t)p * DSTATE + nq));
            f32x4 a4 = o * Cv;
            float acc = (a4[0] + a4[1]) + (a4[2] + a4[3]);
            acc += __shfl_xor(acc, 1);
            acc += __shfl_xor(acc, 2);
            acc += __shfl_xor(acc, 4);
            acc += __shfl_xor(acc, 8);
            if ((t & 15) == 0) yrow[h * HEADDIM + p] = acc + Dk * xp;
        }
        if (h + 1 < NHEADS) {
            #pragma unroll
            for (int it = 0; it < 8; ++it) cur[it] = nxt[it];
        }
    }
    __syncthreads();

    // gate + rmsnorm over HIDDEN
    float vv[4];
    float ssum = 0.f;
    #pragma unroll
    for (int i = 0; i < 4; i++) {
        int j = t + i * 256;
        float z = (float)prow[j];
        float val = yrow[j] * (z / (1.f + expf(-z)));
        vv[i] = val;
        ssum += val * val;
    }
    float tot = block_sum(ssum, red, t);
    float sc = rsqrtf(tot / (float)HIDDEN + EPS);
    #pragma unroll
    for (int i = 0; i < 4; i++) {
        int j = t + i * 256;
        Gb[(size_t)b * HIDDEN + j] = (__bf16)(vv[i] * sc * pw[j]);
    }
}

// ---------------- launch ----------------
extern "C" void kernel_launch(void* const* d_in, const int* in_sizes, int n_in,
                              void* d_out, int out_size, void* d_ws, size_t ws_size,
                              hipStream_t stream) {
    const float* stoch      = (const float*)d_in[0];
    const float* deter      = (const float*)d_in[1];
    const float* action     = (const float*)d_in[2];
    const float* conv_state = (const float*)d_in[3];
    const float* ssm_state  = (const float*)d_in[4];
    const float* in_proj_w  = (const float*)d_in[5];
    const float* in_proj_b  = (const float*)d_in[6];
    const float* in_norm_w  = (const float*)d_in[7];
    const float* blk_norm_w = (const float*)d_in[8];
    const float* blk_in_w   = (const float*)d_in[9];
    const float* blk_conv_w = (const float*)d_in[10];
    const float* blk_conv_b = (const float*)d_in[11];
    const float* blk_A_log  = (const float*)d_in[12];
    const float* blk_D      = (const float*)d_in[13];
    const float* blk_dt_bias= (const float*)d_in[14];
    const float* blk_post_norm_w = (const float*)d_in[15];
    const float* blk_out_w  = (const float*)d_in[16];
    const float* blk_out_b  = (const float*)d_in[17];
    const float* out_norm_w = (const float*)d_in[18];

    float* out_deter = (float*)d_out;
    float* out_cs    = out_deter + (size_t)B_SZ * DETER;
    float* out_ss    = out_cs + (size_t)2 * B_SZ * CONV_DIM * 3;

    char* ws = (char*)d_ws;
    __bf16* Wb_inproj = (__bf16*)ws;  ws += (size_t)TOKEN_DIM * KIN * 2;
    float*  X         = (float*)ws;   ws += (size_t)B_SZ * TOKEN_DIM * 4;
    __bf16* Hb        = (__bf16*)ws;  ws += (size_t)B_SZ * TOKEN_DIM * 2;
    __bf16* PROJ      = (__bf16*)ws;  ws += (size_t)B_SZ * IPP2 * 2;
    __bf16* Gb        = (__bf16*)ws;  ws += (size_t)B_SZ * HIDDEN * 2;
    float*  PART      = (float*)ws;   ws += (size_t)2 * B_SZ * TOKEN_DIM * 4;  // split-K=2 partials
    __bf16* INPb = PROJ;   // alias: consumed by input GEMM before PROJ written

    // 0. in_proj weights -> bf16 + input row build
    {
        int total = N0C + N3C;
        prep_small<<<(total + 255) / 256, 256, 0, stream>>>(
            in_proj_w, stoch, action, Wb_inproj, INPb);
    }
    // 1. input GEMM (split-K 2: 17 steps -> 9,8) + fused reduce/rms/silu/rms
    {
        dim3 grid(TOKEN_DIM / 64, B_SZ / 128, 2);
        gemm_v2<true, false, float><<<grid, 256, 0, stream>>>(
            INPb, Wb_inproj, nullptr, PART, B_SZ, TOKEN_DIM, TOKEN_DIM, KIN, 9);
        reduce_in_kernel<<<B_SZ, 256, 0, stream>>>(PART, in_proj_b, in_norm_w,
                                                   blk_norm_w, X, Hb);
    }

    for (int l = 0; l < 2; ++l) {
        const float* iw  = blk_in_w + (size_t)l * IN_PROJ_DIM * TOKEN_DIM;  // f32 direct
        const float* cw  = blk_conv_w + (size_t)l * CONV_DIM * 4;
        const float* cbv = blk_conv_b + (size_t)l * CONV_DIM;
        const float* alog= blk_A_log + (size_t)l * NHEADS;
        const float* Dvv = blk_D + (size_t)l * NHEADS;
        const float* dtb = blk_dt_bias + (size_t)l * NHEADS;
        const float* pw  = blk_post_norm_w + (size_t)l * HIDDEN;
        const float* ow  = blk_out_w + (size_t)l * TOKEN_DIM * HIDDEN;      // f32 direct
        const float* ob  = blk_out_b + (size_t)l * TOKEN_DIM;
        const float* cs_in = conv_state + (size_t)l * B_SZ * CONV_DIM * 3;
        const float* ss_in = ssm_state + (size_t)l * B_SZ * NHEADS * HEADDIM * DSTATE;
        float* cs_out = out_cs + (size_t)l * B_SZ * CONV_DIM * 3;
        float* ss_out = out_ss + (size_t)l * B_SZ * NHEADS * HEADDIM * DSTATE;

        // in-proj GEMM (no split): N=2304 (2184 real rows), f32 W, bf16 out
        {
            dim3 grid(IPP2 / 64, B_SZ / 128);
            gemm_v2<false, true, __bf16><<<grid, 256, 0, stream>>>(
                Hb, iw, nullptr, PROJ, B_SZ, IPP2, IN_PROJ_DIM, TOKEN_DIM, 0);
        }
        // fused conv + ssm + gate-rmsnorm
        conv_ssm_gate_kernel<<<B_SZ, 256, 0, stream>>>(
            cs_in, PROJ, cw, cbv, dtb, alog, Dvv, pw, ss_in, cs_out, ss_out, Gb);
        // out GEMM (split-K 2: 16 steps -> 8,8), f32 W
        {
            dim3 grid(TOKEN_DIM / 64, B_SZ / 128, 2);
            gemm_v2<true, true, float><<<grid, 256, 0, stream>>>(
                Gb, ow, nullptr, PART, B_SZ, TOKEN_DIM, TOKEN_DIM, HIDDEN, 8);
        }
        // fused residual + rms (next layer or final tape)
        if (l == 0) {
            reduce_out_kernel<0><<<B_SZ, 256, 0, stream>>>(
                PART, ob, X, blk_norm_w + TOKEN_DIM, X, Hb, nullptr, nullptr);
        } else {
            reduce_out_kernel<1><<<B_SZ, 256, 0, stream>>>(
                PART, ob, X, out_norm_w, nullptr, nullptr, deter, out_deter);
        }
    }
}

// Round 9
// 292.738 us; speedup vs baseline: 1.0172x; 1.0172x over previous
//
#include <hip/hip_runtime.h>
#include <hip/hip_bf16.h>
#include <math.h>

#define B_SZ 1024
#define STOCH 1024
#define ACT 32
#define DETER 4096
#define TOKEN_DIM 512
#define HIDDEN 1024
#define NHEADS 8
#define HEADDIM 128
#define DSTATE 64
#define CONV_DIM 1152
#define IN_PROJ_DIM 2184
#define IPP2 2304         // in_proj N padded to 36*64
#define KIN 1088          // input GEMM K padded to 17*64
#define EPS 0.0001f

typedef float f32x4 __attribute__((ext_vector_type(4)));
typedef __bf16 bf16x8 __attribute__((ext_vector_type(8)));
typedef __bf16 bf16x4 __attribute__((ext_vector_type(4)));

// ---------------- fused prep: weights -> bf16 (padded) + input row build ----------------
#define N0C (512 * KIN / 4)
#define N1C (2 * IPP2 * TOKEN_DIM / 4)
#define N2C (2 * TOKEN_DIM * HIDDEN / 4)
#define N3C (B_SZ * KIN / 4)
__global__ __launch_bounds__(256) void prep_all(
    const float* __restrict__ inproj, const float* __restrict__ blkin,
    const float* __restrict__ blkout,
    const float* __restrict__ stoch, const float* __restrict__ action,
    __bf16* __restrict__ w0, __bf16* __restrict__ w1, __bf16* __restrict__ w2,
    __bf16* __restrict__ inp)
{
    int i = blockIdx.x * 256 + threadIdx.x;
    bf16x4 o = { (__bf16)0.f, (__bf16)0.f, (__bf16)0.f, (__bf16)0.f };
    if (i < N0C) {
        int idx = i * 4;
        int rr = idx / KIN, cc = idx % KIN;
        if (cc < STOCH + ACT) {
            float4 v = *(const float4*)(inproj + (size_t)rr * (STOCH + ACT) + cc);
            o = bf16x4{ (__bf16)v.x, (__bf16)v.y, (__bf16)v.z, (__bf16)v.w };
        }
        ((bf16x4*)w0)[i] = o;
    } else if (i < N0C + N1C) {
        int j = i - N0C;
        int idx = j * 4;
        int li  = idx / (IPP2 * TOKEN_DIM);
        int rem = idx % (IPP2 * TOKEN_DIM);
        int rr  = rem / TOKEN_DIM, cc = rem % TOKEN_DIM;
        if (rr < IN_PROJ_DIM) {
            float4 v = *(const float4*)(blkin + ((size_t)li * IN_PROJ_DIM + rr) * TOKEN_DIM + cc);
            o = bf16x4{ (__bf16)v.x, (__bf16)v.y, (__bf16)v.z, (__bf16)v.w };
        }
        ((bf16x4*)w1)[j] = o;
    } else if (i < N0C + N1C + N2C) {
        int j = i - N0C - N1C;
        float4 v = ((const float4*)blkout)[j];
        o = bf16x4{ (__bf16)v.x, (__bf16)v.y, (__bf16)v.z, (__bf16)v.w };
        ((bf16x4*)w2)[j] = o;
    } else if (i < N0C + N1C + N2C + N3C) {
        int j = i - N0C - N1C - N2C;
        int idx = j * 4;
        int b = idx / KIN, c = idx % KIN;
        if (c < STOCH) {
            float4 v = *(const float4*)(stoch + (size_t)b * STOCH + c);
            o = bf16x4{ (__bf16)v.x, (__bf16)v.y, (__bf16)v.z, (__bf16)v.w };
        } else if (c < STOCH + ACT) {
            float4 v = *(const float4*)(action + (size_t)b * ACT + (c - STOCH));
            float4 m;
            m.x = fabsf(v.x) > 1.f ? fabsf(v.x) : 1.f;
            m.y = fabsf(v.y) > 1.f ? fabsf(v.y) : 1.f;
            m.z = fabsf(v.z) > 1.f ? fabsf(v.z) : 1.f;
            m.w = fabsf(v.w) > 1.f ? fabsf(v.w) : 1.f;
            o = bf16x4{ (__bf16)(v.x / m.x), (__bf16)(v.y / m.y),
                        (__bf16)(v.z / m.z), (__bf16)(v.w / m.w) };
        }
        ((bf16x4*)inp)[j] = o;
    }
}

// ---------------- GEMM v2: 128x64 wg tile, wave 32x64, optional split-K ----------
// C = A_bf16(MxK) @ W_bf16(NxK)^T   M%128==0, N%64==0, K%64==0
template<bool SPLIT, typename OutT>
__global__ __launch_bounds__(256) void gemm_v2(
    const __bf16* __restrict__ A,
    const __bf16* __restrict__ W,
    const float* __restrict__ bias,   // only used when !SPLIT (may be null)
    OutT* __restrict__ C,             // !SPLIT: MxN ; SPLIT: [z][M][N]
    int M, int N, int K, int chunk_steps)
{
    __shared__ __bf16 As[128 * 64];   // 128 rows x 128B, XOR-swizzled
    __shared__ __bf16 Ws[64 * 64];
    const int tid = threadIdx.x;
    const int bn = blockIdx.x * 64;
    const int bm = blockIdx.y * 128;
    const int nsteps = K >> 6;
    int s_begin = 0, s_end = nsteps;
    OutT* Cout = C;
    if (SPLIT) {
        int z = blockIdx.z;
        s_begin = z * chunk_steps;
        int se = s_begin + chunk_steps;
        s_end = se < nsteps ? se : nsteps;
        Cout = C + (size_t)z * M * N;
    }

    const int wid = tid >> 6;
    const int lane = tid & 63;
    const int wr = wid * 32;
    const int r = lane & 15;
    const int kb = (lane >> 4) * 16;

    const int row0 = tid >> 3;
    const int colb = (tid & 7) * 16;
    const int wof = row0 * 128 + (colb ^ ((row0 & 7) << 4));
    char* Asb = (char*)As;
    char* Wsb = (char*)Ws;

    const __bf16* gA = A + (size_t)(bm + row0) * K + (s_begin << 6) + (colb >> 1);
    const __bf16* gW = W + (size_t)(bn + row0) * K + (s_begin << 6) + (colb >> 1);
    const size_t aK32 = (size_t)32 * K;

    const int ar0 = wr + r;
    const int ar1 = wr + 16 + r;
    const int aswz = (ar0 & 7) << 4;
    const int bswz = (r & 7) << 4;

    f32x4 acc[2][4] = {};
    bf16x8 va0 = *(const bf16x8*)(gA);
    bf16x8 va1 = *(const bf16x8*)(gA + aK32);
    bf16x8 va2 = *(const bf16x8*)(gA + 2 * aK32);
    bf16x8 va3 = *(const bf16x8*)(gA + 3 * aK32);
    bf16x8 vw0 = *(const bf16x8*)(gW);
    bf16x8 vw1 = *(const bf16x8*)(gW + aK32);

    for (int s = s_begin; s < s_end; ++s) {
        __syncthreads();
        *(bf16x8*)(Asb + wof) = va0;
        *(bf16x8*)(Asb + wof + 32 * 128) = va1;
        *(bf16x8*)(Asb + wof + 64 * 128) = va2;
        *(bf16x8*)(Asb + wof + 96 * 128) = va3;
        *(bf16x8*)(Wsb + wof) = vw0;
        *(bf16x8*)(Wsb + wof + 32 * 128) = vw1;
        __syncthreads();
        if (s + 1 < s_end) {
            const int ko = (s + 1 - s_begin) << 6;
            va0 = *(const bf16x8*)(gA + ko);
            va1 = *(const bf16x8*)(gA + aK32 + ko);
            va2 = *(const bf16x8*)(gA + 2 * aK32 + ko);
            va3 = *(const bf16x8*)(gA + 3 * aK32 + ko);
            vw0 = *(const bf16x8*)(gW + ko);
            vw1 = *(const bf16x8*)(gW + aK32 + ko);
        }
        #pragma unroll
        for (int ks = 0; ks < 2; ++ks) {
            const int cb = ks * 64 + kb;
            bf16x8 a0 = *(const bf16x8*)(Asb + ar0 * 128 + (cb ^ aswz));
            bf16x8 a1 = *(const bf16x8*)(Asb + ar1 * 128 + (cb ^ aswz));
            bf16x8 b0 = *(const bf16x8*)(Wsb + r * 128 + (cb ^ bswz));
            bf16x8 b1 = *(const bf16x8*)(Wsb + (r + 16) * 128 + (cb ^ bswz));
            bf16x8 b2 = *(const bf16x8*)(Wsb + (r + 32) * 128 + (cb ^ bswz));
            bf16x8 b3 = *(const bf16x8*)(Wsb + (r + 48) * 128 + (cb ^ bswz));
            acc[0][0] = __builtin_amdgcn_mfma_f32_16x16x32_bf16(a0, b0, acc[0][0], 0, 0, 0);
            acc[0][1] = __builtin_amdgcn_mfma_f32_16x16x32_bf16(a0, b1, acc[0][1], 0, 0, 0);
            acc[0][2] = __builtin_amdgcn_mfma_f32_16x16x32_bf16(a0, b2, acc[0][2], 0, 0, 0);
            acc[0][3] = __builtin_amdgcn_mfma_f32_16x16x32_bf16(a0, b3, acc[0][3], 0, 0, 0);
            acc[1][0] = __builtin_amdgcn_mfma_f32_16x16x32_bf16(a1, b0, acc[1][0], 0, 0, 0);
            acc[1][1] = __builtin_amdgcn_mfma_f32_16x16x32_bf16(a1, b1, acc[1][1], 0, 0, 0);
            acc[1][2] = __builtin_amdgcn_mfma_f32_16x16x32_bf16(a1, b2, acc[1][2], 0, 0, 0);
            acc[1][3] = __builtin_amdgcn_mfma_f32_16x16x32_bf16(a1, b3, acc[1][3], 0, 0, 0);
        }
    }

    const int cr = (lane >> 4) * 4;
    const int cc = lane & 15;
    #pragma unroll
    for (int mi = 0; mi < 2; mi++) {
        #pragma unroll
        for (int ni = 0; ni < 4; ni++) {
            int n = bn + ni * 16 + cc;
            #pragma unroll
            for (int j = 0; j < 4; j++) {
                int m = bm + wr + mi * 16 + cr + j;
                float v = acc[mi][ni][j];
                if (!SPLIT && bias) v += bias[n];
                Cout[(size_t)m * N + n] = (OutT)v;
            }
        }
    }
}

// ---------------- block-wide sum helper (256 threads) ----------------
__device__ __forceinline__ float block_sum(float v, float* red, int t) {
    #pragma unroll
    for (int off = 32; off >= 1; off >>= 1) v += __shfl_xor(v, off);
    if ((t & 63) == 0) red[t >> 6] = v;
    __syncthreads();
    float tot = red[0] + red[1] + red[2] + red[3];
    __syncthreads();
    return tot;
}

// ---------------- reduce_in: X = silu(rmsnorm(ΣP+bias, inw)); Hb = bf16(rmsnorm(X, nw)) ----
__global__ __launch_bounds__(256) void reduce_in_kernel(
    const float* __restrict__ P,      // [4][B][512]
    const float* __restrict__ bias,
    const float* __restrict__ inw,
    const float* __restrict__ nw,
    float* __restrict__ X, __bf16* __restrict__ Hb)
{
    __shared__ float red[4];
    int b = blockIdx.x, t = threadIdx.x;
    const size_t stride = (size_t)B_SZ * TOKEN_DIM;
    float h[2];
    float ss = 0.f;
    #pragma unroll
    for (int i = 0; i < 2; i++) {
        int c = t + i * 256;
        size_t o = (size_t)b * TOKEN_DIM + c;
        float v = P[o] + P[o + stride] + P[o + 2 * stride] + P[o + 3 * stride] + bias[c];
        h[i] = v;
        ss += v * v;
    }
    float tot = block_sum(ss, red, t);
    float sc = rsqrtf(tot / (float)TOKEN_DIM + EPS);
    float ss2 = 0.f;
    #pragma unroll
    for (int i = 0; i < 2; i++) {
        int c = t + i * 256;
        float v = h[i] * sc * inw[c];
        v = v / (1.f + expf(-v));        // silu
        h[i] = v;
        X[(size_t)b * TOKEN_DIM + c] = v;
        ss2 += v * v;
    }
    float tot2 = block_sum(ss2, red, t);
    float sc2 = rsqrtf(tot2 / (float)TOKEN_DIM + EPS);
    #pragma unroll
    for (int i = 0; i < 2; i++) {
        int c = t + i * 256;
        Hb[(size_t)b * TOKEN_DIM + c] = (__bf16)(h[i] * sc2 * nw[c]);
    }
}

// ---------------- reduce_out: newX = X + ΣP + ob; MODE0: X,Hb=rms(newX,w); MODE1: final tape ----
template<int MODE>
__global__ __launch_bounds__(256) void reduce_out_kernel(
    const float* __restrict__ P,      // [4][B][512]
    const float* __restrict__ ob,
    const float* __restrict__ Xin,
    const float* __restrict__ w,
    float* __restrict__ X,
    __bf16* __restrict__ Hb,
    const float* __restrict__ deter,
    float* __restrict__ out)
{
    __shared__ float red[4];
    int b = blockIdx.x, t = threadIdx.x;
    const size_t stride = (size_t)B_SZ * TOKEN_DIM;
    float h[2];
    float ss = 0.f;
    #pragma unroll
    for (int i = 0; i < 2; i++) {
        int c = t + i * 256;
        size_t o = (size_t)b * TOKEN_DIM + c;
        float v = Xin[o] + P[o] + P[o + stride] + P[o + 2 * stride] + P[o + 3 * stride] + ob[c];
        h[i] = v;
        ss += v * v;
    }
    float tot = block_sum(ss, red, t);
    float sc = rsqrtf(tot / (float)TOKEN_DIM + EPS);
    if (MODE == 0) {
        #pragma unroll
        for (int i = 0; i < 2; i++) {
            int c = t + i * 256;
            size_t o = (size_t)b * TOKEN_DIM + c;
            X[o] = h[i];
            Hb[o] = (__bf16)(h[i] * sc * w[c]);
        }
    } else {
        #pragma unroll
        for (int i = 0; i < 2; i++) {
            int c = t + i * 256;
            out[(size_t)b * DETER + 3584 + c] = h[i] * sc * w[c];
        }
        const float4* src = (const float4*)(deter + (size_t)b * DETER + TOKEN_DIM);
        float4* dst = (float4*)(out + (size_t)b * DETER);
        #pragma unroll
        for (int j = 0; j < 4; ++j) {
            int idx = t + j * 256;
            if (idx < 896) dst[idx] = src[idx];
        }
    }
}

// ---------------- fused conv + ssm + gate-rmsnorm (one block per batch row) ----------------
// v5 = r7 pipeline + vectorized conv phase (3xfloat4 cs r/w, bf16x4 proj) and
//      vectorized gate phase (bf16x4 z, float4 yrow, 8B Gb store).
__global__ __launch_bounds__(256, 4) void conv_ssm_gate_kernel(
    const float* __restrict__ cs,      // B x CONV_DIM x 3
    const __bf16* __restrict__ proj,   // B x IPP2 (bf16)
    const float* __restrict__ cw,      // CONV_DIM x 4
    const float* __restrict__ cb,      // CONV_DIM
    const float* __restrict__ dtb,     // NHEADS
    const float* __restrict__ alog,    // NHEADS
    const float* __restrict__ Dv,      // NHEADS
    const float* __restrict__ pw,      // HIDDEN
    const float* __restrict__ ss,      // B x NHEADS x HEADDIM x DSTATE
    float* __restrict__ new_cs,
    float* __restrict__ new_ss,
    __bf16* __restrict__ Gb)           // B x HIDDEN
{
    __shared__ float convs[CONV_DIM];  // x(1024) | B(64) | C(64)
    __shared__ float yrow[HIDDEN];
    __shared__ float dts[NHEADS], dAs[NHEADS], dvs[NHEADS];
    __shared__ float red[4];

    int b = blockIdx.x, t = threadIdx.x;
    const __bf16* prow = proj + (size_t)b * IPP2;

    const int p0 = t >> 4;            // 0..15
    const int nq = (t & 15) * 4;      // 0..60
    const float* basep = ss + (size_t)b * NHEADS * HEADDIM * DSTATE;
    float* baseo = new_ss + (size_t)b * NHEADS * HEADDIM * DSTATE;

    // prefetch head 0 state (in flight during conv phase)
    f32x4 cur[8], nxt[8];
    #pragma unroll
    for (int it = 0; it < 8; ++it) {
        int p = it * 16 + p0;
        cur[it] = __builtin_nontemporal_load((const f32x4*)(basep + (size_t)p * DSTATE + nq));
    }

    if (t < NHEADS) {
        float dtr = (float)prow[HIDDEN + CONV_DIM + t] + dtb[t];
        float dt = dtr > 20.f ? dtr : log1pf(expf(dtr));
        dts[t] = dt;
        dAs[t] = expf(dt * -expf(alog[t]));
        dvs[t] = Dv[t];
    }

    // conv phase, pass 1: channels 0..1023, 4 per thread, vectorized
    {
        const int c0 = t * 4;
        const float* s = cs + ((size_t)b * CONV_DIM + c0) * 3;     // 12 floats
        f32x4 sa = __builtin_nontemporal_load((const f32x4*)(s));
        f32x4 sb = __builtin_nontemporal_load((const f32x4*)(s + 4));
        f32x4 sc4 = __builtin_nontemporal_load((const f32x4*)(s + 8));
        bf16x4 xb4 = *(const bf16x4*)(prow + HIDDEN + c0);
        float xbc[4] = { (float)xb4[0], (float)xb4[1], (float)xb4[2], (float)xb4[3] };
        float sv[12] = { sa[0], sa[1], sa[2], sa[3], sb[0], sb[1], sb[2], sb[3],
                         sc4[0], sc4[1], sc4[2], sc4[3] };
        f32x4 outv;
        #pragma unroll
        for (int k = 0; k < 4; ++k) {
            float4 wv = *(const float4*)(cw + (c0 + k) * 4);
            float v = wv.x * sv[k * 3] + wv.y * sv[k * 3 + 1] + wv.z * sv[k * 3 + 2]
                    + wv.w * xbc[k] + cb[c0 + k];
            outv[k] = v / (1.f + expf(-v));
        }
        *(f32x4*)&convs[c0] = outv;
        float* nc = new_cs + ((size_t)b * CONV_DIM + c0) * 3;
        f32x4 o0 = { sv[1], sv[2], xbc[0], sv[4] };
        f32x4 o1 = { sv[5], xbc[1], sv[7], sv[8] };
        f32x4 o2 = { xbc[2], sv[10], sv[11], xbc[3] };
        __builtin_nontemporal_store(o0, (f32x4*)(nc));
        __builtin_nontemporal_store(o1, (f32x4*)(nc + 4));
        __builtin_nontemporal_store(o2, (f32x4*)(nc + 8));
    }
    // conv phase, pass 2: channels 1024..1151 (B and C), threads 0..127
    if (t < 128) {
        const int c = 1024 + t;
        const float* s = cs + ((size_t)b * CONV_DIM + c) * 3;
        float s0 = s[0], s1 = s[1], s2 = s[2];
        float xbc = (float)prow[HIDDEN + c];
        float4 wv = *(const float4*)(cw + c * 4);
        float v = wv.x * s0 + wv.y * s1 + wv.z * s2 + wv.w * xbc + cb[c];
        convs[c] = v / (1.f + expf(-v));
        float* nc = new_cs + ((size_t)b * CONV_DIM + c) * 3;
        nc[0] = s1; nc[1] = s2; nc[2] = xbc;
    }
    __syncthreads();

    const f32x4 Bv = *(const f32x4*)&convs[HIDDEN + nq];
    const f32x4 Cv = *(const f32x4*)&convs[HIDDEN + DSTATE + nq];

    #pragma unroll
    for (int h = 0; h < NHEADS; ++h) {
        if (h + 1 < NHEADS) {
            #pragma unroll
            for (int it = 0; it < 8; ++it) {
                int p = it * 16 + p0;
                nxt[it] = __builtin_nontemporal_load(
                    (const f32x4*)(basep + (size_t)((h + 1) * HEADDIM + p) * DSTATE + nq));
            }
        }
        const float dt = dts[h], dA = dAs[h], Dk = dvs[h];
        float* op = baseo + (size_t)h * HEADDIM * DSTATE;
        #pragma unroll
        for (int it = 0; it < 8; ++it) {
            int p = it * 16 + p0;
            float xp = convs[h * HEADDIM + p];
            float dtx = dt * xp;
            f32x4 o = cur[it] * dA + dtx * Bv;
            __builtin_nontemporal_store(o, (f32x4*)(op + (size_t)p * DSTATE + nq));
            f32x4 a4 = o * Cv;
            float acc = (a4[0] + a4[1]) + (a4[2] + a4[3]);
            acc += __shfl_xor(acc, 1);
            acc += __shfl_xor(acc, 2);
            acc += __shfl_xor(acc, 4);
            acc += __shfl_xor(acc, 8);
            if ((t & 15) == 0) yrow[h * HEADDIM + p] = acc + Dk * xp;
        }
        if (h + 1 < NHEADS) {
            #pragma unroll
            for (int it = 0; it < 8; ++it) cur[it] = nxt[it];
        }
    }
    __syncthreads();

    // gate + rmsnorm over HIDDEN (vectorized: 4 consecutive per thread)
    const int j0 = t * 4;
    bf16x4 z4 = *(const bf16x4*)(prow + j0);
    f32x4 y4 = *(const f32x4*)&yrow[j0];
    f32x4 vv;
    float ssum = 0.f;
    #pragma unroll
    for (int k = 0; k < 4; ++k) {
        float z = (float)z4[k];
        float val = y4[k] * (z / (1.f + expf(-z)));
        vv[k] = val;
        ssum += val * val;
    }
    float tot = block_sum(ssum, red, t);
    float sc = rsqrtf(tot / (float)HIDDEN + EPS);
    float4 pw4 = *(const float4*)(pw + j0);
    bf16x4 g4 = { (__bf16)(vv[0] * sc * pw4.x), (__bf16)(vv[1] * sc * pw4.y),
                  (__bf16)(vv[2] * sc * pw4.z), (__bf16)(vv[3] * sc * pw4.w) };
    *(bf16x4*)(Gb + (size_t)b * HIDDEN + j0) = g4;
}

// ---------------- launch ----------------
extern "C" void kernel_launch(void* const* d_in, const int* in_sizes, int n_in,
                              void* d_out, int out_size, void* d_ws, size_t ws_size,
                              hipStream_t stream) {
    const float* stoch      = (const float*)d_in[0];
    const float* deter      = (const float*)d_in[1];
    const float* action     = (const float*)d_in[2];
    const float* conv_state = (const float*)d_in[3];
    const float* ssm_state  = (const float*)d_in[4];
    const float* in_proj_w  = (const float*)d_in[5];
    const float* in_proj_b  = (const float*)d_in[6];
    const float* in_norm_w  = (const float*)d_in[7];
    const float* blk_norm_w = (const float*)d_in[8];
    const float* blk_in_w   = (const float*)d_in[9];
    const float* blk_conv_w = (const float*)d_in[10];
    const float* blk_conv_b = (const float*)d_in[11];
    const float* blk_A_log  = (const float*)d_in[12];
    const float* blk_D      = (const float*)d_in[13];
    const float* blk_dt_bias= (const float*)d_in[14];
    const float* blk_post_norm_w = (const float*)d_in[15];
    const float* blk_out_w  = (const float*)d_in[16];
    const float* blk_out_b  = (const float*)d_in[17];
    const float* out_norm_w = (const float*)d_in[18];

    float* out_deter = (float*)d_out;
    float* out_cs    = out_deter + (size_t)B_SZ * DETER;
    float* out_ss    = out_cs + (size_t)2 * B_SZ * CONV_DIM * 3;

    char* ws = (char*)d_ws;
    __bf16* Wb_inproj = (__bf16*)ws;  ws += (size_t)TOKEN_DIM * KIN * 2;
    __bf16* Wb_blkin  = (__bf16*)ws;  ws += (size_t)2 * IPP2 * TOKEN_DIM * 2;
    __bf16* Wb_blkout = (__bf16*)ws;  ws += (size_t)2 * TOKEN_DIM * HIDDEN * 2;
    float*  X         = (float*)ws;   ws += (size_t)B_SZ * TOKEN_DIM * 4;
    __bf16* Hb        = (__bf16*)ws;  ws += (size_t)B_SZ * TOKEN_DIM * 2;
    __bf16* PROJ      = (__bf16*)ws;  ws += (size_t)B_SZ * IPP2 * 2;    // bf16
    __bf16* Gb        = (__bf16*)ws;  ws += (size_t)B_SZ * HIDDEN * 2;
    float*  PART      = (float*)ws;   ws += (size_t)4 * B_SZ * TOKEN_DIM * 4;
    __bf16* INPb = PROJ;   // alias: consumed by input GEMM before PROJ written

    // 0. weights -> bf16 (padded) + input row build (one kernel)
    {
        int total = N0C + N1C + N2C + N3C;
        prep_all<<<(total + 255) / 256, 256, 0, stream>>>(
            in_proj_w, blk_in_w, blk_out_w, stoch, action,
            Wb_inproj, Wb_blkin, Wb_blkout, INPb);
    }
    // 1. input GEMM (split-K 4: 17 steps -> 5,5,5,2) + fused reduce/rms/silu/rms
    {
        dim3 grid(TOKEN_DIM / 64, B_SZ / 128, 4);
        gemm_v2<true, float><<<grid, 256, 0, stream>>>(INPb, Wb_inproj, nullptr, PART,
                                                       B_SZ, TOKEN_DIM, KIN, 5);
        reduce_in_kernel<<<B_SZ, 256, 0, stream>>>(PART, in_proj_b, in_norm_w,
                                                   blk_norm_w, X, Hb);
    }

    for (int l = 0; l < 2; ++l) {
        const __bf16* iw = Wb_blkin + (size_t)l * IPP2 * TOKEN_DIM;
        const float* cw  = blk_conv_w + (size_t)l * CONV_DIM * 4;
        const float* cbv = blk_conv_b + (size_t)l * CONV_DIM;
        const float* alog= blk_A_log + (size_t)l * NHEADS;
        const float* Dvv = blk_D + (size_t)l * NHEADS;
        const float* dtb = blk_dt_bias + (size_t)l * NHEADS;
        const float* pw  = blk_post_norm_w + (size_t)l * HIDDEN;
        const __bf16* ow = Wb_blkout + (size_t)l * TOKEN_DIM * HIDDEN;
        const float* ob  = blk_out_b + (size_t)l * TOKEN_DIM;
        const float* cs_in = conv_state + (size_t)l * B_SZ * CONV_DIM * 3;
        const float* ss_in = ssm_state + (size_t)l * B_SZ * NHEADS * HEADDIM * DSTATE;
        float* cs_out = out_cs + (size_t)l * B_SZ * CONV_DIM * 3;
        float* ss_out = out_ss + (size_t)l * B_SZ * NHEADS * HEADDIM * DSTATE;

        // in-proj GEMM (no split): N=2304, bf16 out
        {
            dim3 grid(IPP2 / 64, B_SZ / 128);
            gemm_v2<false, __bf16><<<grid, 256, 0, stream>>>(Hb, iw, nullptr, PROJ,
                                                             B_SZ, IPP2, TOKEN_DIM, 0);
        }
        // fused conv + ssm + gate-rmsnorm
        conv_ssm_gate_kernel<<<B_SZ, 256, 0, stream>>>(
            cs_in, PROJ, cw, cbv, dtb, alog, Dvv, pw, ss_in, cs_out, ss_out, Gb);
        // out GEMM (split-K 4: 16 steps -> 4 each)
        {
            dim3 grid(TOKEN_DIM / 64, B_SZ / 128, 4);
            gemm_v2<true, float><<<grid, 256, 0, stream>>>(Gb, ow, nullptr, PART,
                                                           B_SZ, TOKEN_DIM, HIDDEN, 4);
        }
        // fused residual + rms (next layer or final tape)
        if (l == 0) {
            reduce_out_kernel<0><<<B_SZ, 256, 0, stream>>>(
                PART, ob, X, blk_norm_w + TOKEN_DIM, X, Hb, nullptr, nullptr);
        } else {
            reduce_out_kernel<1><<<B_SZ, 256, 0, stream>>>(
                PART, ob, X, out_norm_w, nullptr, nullptr, deter, out_deter);
        }
    }
}

// Round 10
// 280.102 us; speedup vs baseline: 1.0631x; 1.0451x over previous
//
#include <hip/hip_runtime.h>
#include <hip/hip_bf16.h>
#include <math.h>

#define B_SZ 1024
#define STOCH 1024
#define ACT 32
#define DETER 4096
#define TOKEN_DIM 512
#define HIDDEN 1024
#define NHEADS 8
#define HEADDIM 128
#define DSTATE 64
#define CONV_DIM 1152
#define IN_PROJ_DIM 2184
#define IPP2 2304         // in_proj N padded to 36*64
#define KIN 1088          // input GEMM K padded to 17*64
#define EPS 0.0001f

typedef float f32x4 __attribute__((ext_vector_type(4)));
typedef __bf16 bf16x8 __attribute__((ext_vector_type(8)));
typedef __bf16 bf16x4 __attribute__((ext_vector_type(4)));

// ---------------- fused prep: weights -> bf16 (padded) + input row build ----------------
#define N0C (512 * KIN / 4)
#define N1C (2 * IPP2 * TOKEN_DIM / 4)
#define N2C (2 * TOKEN_DIM * HIDDEN / 4)
#define N3C (B_SZ * KIN / 4)
__global__ __launch_bounds__(256) void prep_all(
    const float* __restrict__ inproj, const float* __restrict__ blkin,
    const float* __restrict__ blkout,
    const float* __restrict__ stoch, const float* __restrict__ action,
    __bf16* __restrict__ w0, __bf16* __restrict__ w1, __bf16* __restrict__ w2,
    __bf16* __restrict__ inp)
{
    int i = blockIdx.x * 256 + threadIdx.x;
    bf16x4 o = { (__bf16)0.f, (__bf16)0.f, (__bf16)0.f, (__bf16)0.f };
    if (i < N0C) {
        int idx = i * 4;
        int rr = idx / KIN, cc = idx % KIN;
        if (cc < STOCH + ACT) {
            float4 v = *(const float4*)(inproj + (size_t)rr * (STOCH + ACT) + cc);
            o = bf16x4{ (__bf16)v.x, (__bf16)v.y, (__bf16)v.z, (__bf16)v.w };
        }
        ((bf16x4*)w0)[i] = o;
    } else if (i < N0C + N1C) {
        int j = i - N0C;
        int idx = j * 4;
        int li  = idx / (IPP2 * TOKEN_DIM);
        int rem = idx % (IPP2 * TOKEN_DIM);
        int rr  = rem / TOKEN_DIM, cc = rem % TOKEN_DIM;
        if (rr < IN_PROJ_DIM) {
            float4 v = *(const float4*)(blkin + ((size_t)li * IN_PROJ_DIM + rr) * TOKEN_DIM + cc);
            o = bf16x4{ (__bf16)v.x, (__bf16)v.y, (__bf16)v.z, (__bf16)v.w };
        }
        ((bf16x4*)w1)[j] = o;
    } else if (i < N0C + N1C + N2C) {
        int j = i - N0C - N1C;
        float4 v = ((const float4*)blkout)[j];
        o = bf16x4{ (__bf16)v.x, (__bf16)v.y, (__bf16)v.z, (__bf16)v.w };
        ((bf16x4*)w2)[j] = o;
    } else if (i < N0C + N1C + N2C + N3C) {
        int j = i - N0C - N1C - N2C;
        int idx = j * 4;
        int b = idx / KIN, c = idx % KIN;
        if (c < STOCH) {
            float4 v = *(const float4*)(stoch + (size_t)b * STOCH + c);
            o = bf16x4{ (__bf16)v.x, (__bf16)v.y, (__bf16)v.z, (__bf16)v.w };
        } else if (c < STOCH + ACT) {
            float4 v = *(const float4*)(action + (size_t)b * ACT + (c - STOCH));
            float4 m;
            m.x = fabsf(v.x) > 1.f ? fabsf(v.x) : 1.f;
            m.y = fabsf(v.y) > 1.f ? fabsf(v.y) : 1.f;
            m.z = fabsf(v.z) > 1.f ? fabsf(v.z) : 1.f;
            m.w = fabsf(v.w) > 1.f ? fabsf(v.w) : 1.f;
            o = bf16x4{ (__bf16)(v.x / m.x), (__bf16)(v.y / m.y),
                        (__bf16)(v.z / m.z), (__bf16)(v.w / m.w) };
        }
        ((bf16x4*)inp)[j] = o;
    }
}

// ---------------- GEMM v2: 128x64 wg tile, wave 32x64, optional split-K ----------
// C = A_bf16(MxK) @ W_bf16(NxK)^T   M%128==0, N%64==0, K%64==0
template<bool SPLIT, typename OutT>
__global__ __launch_bounds__(256) void gemm_v2(
    const __bf16* __restrict__ A,
    const __bf16* __restrict__ W,
    const float* __restrict__ bias,   // only used when !SPLIT (may be null)
    OutT* __restrict__ C,             // !SPLIT: MxN ; SPLIT: [z][M][N]
    int M, int N, int K, int chunk_steps)
{
    __shared__ __bf16 As[128 * 64];   // 128 rows x 128B, XOR-swizzled
    __shared__ __bf16 Ws[64 * 64];
    const int tid = threadIdx.x;
    const int bn = blockIdx.x * 64;
    const int bm = blockIdx.y * 128;
    const int nsteps = K >> 6;
    int s_begin = 0, s_end = nsteps;
    OutT* Cout = C;
    if (SPLIT) {
        int z = blockIdx.z;
        s_begin = z * chunk_steps;
        int se = s_begin + chunk_steps;
        s_end = se < nsteps ? se : nsteps;
        Cout = C + (size_t)z * M * N;
    }

    const int wid = tid >> 6;
    const int lane = tid & 63;
    const int wr = wid * 32;
    const int r = lane & 15;
    const int kb = (lane >> 4) * 16;

    const int row0 = tid >> 3;
    const int colb = (tid & 7) * 16;
    const int wof = row0 * 128 + (colb ^ ((row0 & 7) << 4));
    char* Asb = (char*)As;
    char* Wsb = (char*)Ws;

    const __bf16* gA = A + (size_t)(bm + row0) * K + (s_begin << 6) + (colb >> 1);
    const __bf16* gW = W + (size_t)(bn + row0) * K + (s_begin << 6) + (colb >> 1);
    const size_t aK32 = (size_t)32 * K;

    const int ar0 = wr + r;
    const int ar1 = wr + 16 + r;
    const int aswz = (ar0 & 7) << 4;
    const int bswz = (r & 7) << 4;

    f32x4 acc[2][4] = {};
    bf16x8 va0 = *(const bf16x8*)(gA);
    bf16x8 va1 = *(const bf16x8*)(gA + aK32);
    bf16x8 va2 = *(const bf16x8*)(gA + 2 * aK32);
    bf16x8 va3 = *(const bf16x8*)(gA + 3 * aK32);
    bf16x8 vw0 = *(const bf16x8*)(gW);
    bf16x8 vw1 = *(const bf16x8*)(gW + aK32);

    for (int s = s_begin; s < s_end; ++s) {
        __syncthreads();
        *(bf16x8*)(Asb + wof) = va0;
        *(bf16x8*)(Asb + wof + 32 * 128) = va1;
        *(bf16x8*)(Asb + wof + 64 * 128) = va2;
        *(bf16x8*)(Asb + wof + 96 * 128) = va3;
        *(bf16x8*)(Wsb + wof) = vw0;
        *(bf16x8*)(Wsb + wof + 32 * 128) = vw1;
        __syncthreads();
        if (s + 1 < s_end) {
            const int ko = (s + 1 - s_begin) << 6;
            va0 = *(const bf16x8*)(gA + ko);
            va1 = *(const bf16x8*)(gA + aK32 + ko);
            va2 = *(const bf16x8*)(gA + 2 * aK32 + ko);
            va3 = *(const bf16x8*)(gA + 3 * aK32 + ko);
            vw0 = *(const bf16x8*)(gW + ko);
            vw1 = *(const bf16x8*)(gW + aK32 + ko);
        }
        #pragma unroll
        for (int ks = 0; ks < 2; ++ks) {
            const int cb = ks * 64 + kb;
            bf16x8 a0 = *(const bf16x8*)(Asb + ar0 * 128 + (cb ^ aswz));
            bf16x8 a1 = *(const bf16x8*)(Asb + ar1 * 128 + (cb ^ aswz));
            bf16x8 b0 = *(const bf16x8*)(Wsb + r * 128 + (cb ^ bswz));
            bf16x8 b1 = *(const bf16x8*)(Wsb + (r + 16) * 128 + (cb ^ bswz));
            bf16x8 b2 = *(const bf16x8*)(Wsb + (r + 32) * 128 + (cb ^ bswz));
            bf16x8 b3 = *(const bf16x8*)(Wsb + (r + 48) * 128 + (cb ^ bswz));
            acc[0][0] = __builtin_amdgcn_mfma_f32_16x16x32_bf16(a0, b0, acc[0][0], 0, 0, 0);
            acc[0][1] = __builtin_amdgcn_mfma_f32_16x16x32_bf16(a0, b1, acc[0][1], 0, 0, 0);
            acc[0][2] = __builtin_amdgcn_mfma_f32_16x16x32_bf16(a0, b2, acc[0][2], 0, 0, 0);
            acc[0][3] = __builtin_amdgcn_mfma_f32_16x16x32_bf16(a0, b3, acc[0][3], 0, 0, 0);
            acc[1][0] = __builtin_amdgcn_mfma_f32_16x16x32_bf16(a1, b0, acc[1][0], 0, 0, 0);
            acc[1][1] = __builtin_amdgcn_mfma_f32_16x16x32_bf16(a1, b1, acc[1][1], 0, 0, 0);
            acc[1][2] = __builtin_amdgcn_mfma_f32_16x16x32_bf16(a1, b2, acc[1][2], 0, 0, 0);
            acc[1][3] = __builtin_amdgcn_mfma_f32_16x16x32_bf16(a1, b3, acc[1][3], 0, 0, 0);
        }
    }

    const int cr = (lane >> 4) * 4;
    const int cc = lane & 15;
    #pragma unroll
    for (int mi = 0; mi < 2; mi++) {
        #pragma unroll
        for (int ni = 0; ni < 4; ni++) {
            int n = bn + ni * 16 + cc;
            #pragma unroll
            for (int j = 0; j < 4; j++) {
                int m = bm + wr + mi * 16 + cr + j;
                float v = acc[mi][ni][j];
                if (!SPLIT && bias) v += bias[n];
                Cout[(size_t)m * N + n] = (OutT)v;
            }
        }
    }
}

// ---------------- block-wide sum helper (256 threads) ----------------
__device__ __forceinline__ float block_sum(float v, float* red, int t) {
    #pragma unroll
    for (int off = 32; off >= 1; off >>= 1) v += __shfl_xor(v, off);
    if ((t & 63) == 0) red[t >> 6] = v;
    __syncthreads();
    float tot = red[0] + red[1] + red[2] + red[3];
    __syncthreads();
    return tot;
}

// ---------------- reduce_in: X = silu(rmsnorm(ΣP+bias, inw)); Hb = bf16(rmsnorm(X, nw)) ----
__global__ __launch_bounds__(256) void reduce_in_kernel(
    const float* __restrict__ P,      // [4][B][512]
    const float* __restrict__ bias,
    const float* __restrict__ inw,
    const float* __restrict__ nw,
    float* __restrict__ X, __bf16* __restrict__ Hb)
{
    __shared__ float red[4];
    int b = blockIdx.x, t = threadIdx.x;
    const size_t stride = (size_t)B_SZ * TOKEN_DIM;
    float h[2];
    float ss = 0.f;
    #pragma unroll
    for (int i = 0; i < 2; i++) {
        int c = t + i * 256;
        size_t o = (size_t)b * TOKEN_DIM + c;
        float v = P[o] + P[o + stride] + P[o + 2 * stride] + P[o + 3 * stride] + bias[c];
        h[i] = v;
        ss += v * v;
    }
    float tot = block_sum(ss, red, t);
    float sc = rsqrtf(tot / (float)TOKEN_DIM + EPS);
    float ss2 = 0.f;
    #pragma unroll
    for (int i = 0; i < 2; i++) {
        int c = t + i * 256;
        float v = h[i] * sc * inw[c];
        v = v / (1.f + expf(-v));        // silu
        h[i] = v;
        X[(size_t)b * TOKEN_DIM + c] = v;
        ss2 += v * v;
    }
    float tot2 = block_sum(ss2, red, t);
    float sc2 = rsqrtf(tot2 / (float)TOKEN_DIM + EPS);
    #pragma unroll
    for (int i = 0; i < 2; i++) {
        int c = t + i * 256;
        Hb[(size_t)b * TOKEN_DIM + c] = (__bf16)(h[i] * sc2 * nw[c]);
    }
}

// ---------------- reduce_out: newX = X + ΣP + ob; MODE0: X,Hb=rms(newX,w); MODE1: final tape ----
template<int MODE>
__global__ __launch_bounds__(256) void reduce_out_kernel(
    const float* __restrict__ P,      // [4][B][512]
    const float* __restrict__ ob,
    const float* __restrict__ Xin,
    const float* __restrict__ w,
    float* __restrict__ X,
    __bf16* __restrict__ Hb,
    const float* __restrict__ deter,
    float* __restrict__ out)
{
    __shared__ float red[4];
    int b = blockIdx.x, t = threadIdx.x;
    const size_t stride = (size_t)B_SZ * TOKEN_DIM;
    float h[2];
    float ss = 0.f;
    #pragma unroll
    for (int i = 0; i < 2; i++) {
        int c = t + i * 256;
        size_t o = (size_t)b * TOKEN_DIM + c;
        float v = Xin[o] + P[o] + P[o + stride] + P[o + 2 * stride] + P[o + 3 * stride] + ob[c];
        h[i] = v;
        ss += v * v;
    }
    float tot = block_sum(ss, red, t);
    float sc = rsqrtf(tot / (float)TOKEN_DIM + EPS);
    if (MODE == 0) {
        #pragma unroll
        for (int i = 0; i < 2; i++) {
            int c = t + i * 256;
            size_t o = (size_t)b * TOKEN_DIM + c;
            X[o] = h[i];
            Hb[o] = (__bf16)(h[i] * sc * w[c]);
        }
    } else {
        #pragma unroll
        for (int i = 0; i < 2; i++) {
            int c = t + i * 256;
            out[(size_t)b * DETER + 3584 + c] = h[i] * sc * w[c];
        }
        const float4* src = (const float4*)(deter + (size_t)b * DETER + TOKEN_DIM);
        float4* dst = (float4*)(out + (size_t)b * DETER);
        #pragma unroll
        for (int j = 0; j < 4; ++j) {
            int idx = t + j * 256;
            if (idx < 896) dst[idx] = src[idx];
        }
    }
}

// ---------------- fused conv + ssm + gate-rmsnorm (one block per batch row) ----------------
// v6 = r7 pipeline (strided coalesced conv phase, head-pipelined SSM)
//      + r9's gate-phase vectorization only (coalesced 8B loads/stores).
__global__ __launch_bounds__(256, 4) void conv_ssm_gate_kernel(
    const float* __restrict__ cs,      // B x CONV_DIM x 3
    const __bf16* __restrict__ proj,   // B x IPP2 (bf16)
    const float* __restrict__ cw,      // CONV_DIM x 4
    const float* __restrict__ cb,      // CONV_DIM
    const float* __restrict__ dtb,     // NHEADS
    const float* __restrict__ alog,    // NHEADS
    const float* __restrict__ Dv,      // NHEADS
    const float* __restrict__ pw,      // HIDDEN
    const float* __restrict__ ss,      // B x NHEADS x HEADDIM x DSTATE
    float* __restrict__ new_cs,
    float* __restrict__ new_ss,
    __bf16* __restrict__ Gb)           // B x HIDDEN
{
    __shared__ float convs[CONV_DIM];  // x(1024) | B(64) | C(64)
    __shared__ float yrow[HIDDEN];
    __shared__ float dts[NHEADS], dAs[NHEADS], dvs[NHEADS];
    __shared__ float red[4];

    int b = blockIdx.x, t = threadIdx.x;
    const __bf16* prow = proj + (size_t)b * IPP2;

    const int p0 = t >> 4;            // 0..15
    const int nq = (t & 15) * 4;      // 0..60
    const float* basep = ss + (size_t)b * NHEADS * HEADDIM * DSTATE;
    float* baseo = new_ss + (size_t)b * NHEADS * HEADDIM * DSTATE;

    // prefetch head 0 state (in flight during conv phase)
    f32x4 cur[8], nxt[8];
    #pragma unroll
    for (int it = 0; it < 8; ++it) {
        int p = it * 16 + p0;
        cur[it] = __builtin_nontemporal_load((const f32x4*)(basep + (size_t)p * DSTATE + nq));
    }

    if (t < NHEADS) {
        float dtr = (float)prow[HIDDEN + CONV_DIM + t] + dtb[t];
        float dt = dtr > 20.f ? dtr : log1pf(expf(dtr));
        dts[t] = dt;
        dAs[t] = expf(dt * -expf(alog[t]));
        dvs[t] = Dv[t];
    }
    // conv over 1152 channels (strided per-lane: per-instruction coalesced)
    for (int c = t; c < CONV_DIM; c += 256) {
        const float* s = cs + ((size_t)b * CONV_DIM + c) * 3;
        float s0 = s[0], s1 = s[1], s2 = s[2];
        float xbc = (float)prow[HIDDEN + c];
        float4 wv = *(const float4*)(cw + c * 4);
        float v = wv.x * s0 + wv.y * s1 + wv.z * s2 + wv.w * xbc + cb[c];
        v = v / (1.f + expf(-v));
        convs[c] = v;
        float* nc = new_cs + ((size_t)b * CONV_DIM + c) * 3;
        nc[0] = s1; nc[1] = s2; nc[2] = xbc;
    }
    __syncthreads();

    const f32x4 Bv = *(const f32x4*)&convs[HIDDEN + nq];
    const f32x4 Cv = *(const f32x4*)&convs[HIDDEN + DSTATE + nq];

    #pragma unroll
    for (int h = 0; h < NHEADS; ++h) {
        if (h + 1 < NHEADS) {
            #pragma unroll
            for (int it = 0; it < 8; ++it) {
                int p = it * 16 + p0;
                nxt[it] = __builtin_nontemporal_load(
                    (const f32x4*)(basep + (size_t)((h + 1) * HEADDIM + p) * DSTATE + nq));
            }
        }
        const float dt = dts[h], dA = dAs[h], Dk = dvs[h];
        float* op = baseo + (size_t)h * HEADDIM * DSTATE;
        #pragma unroll
        for (int it = 0; it < 8; ++it) {
            int p = it * 16 + p0;
            float xp = convs[h * HEADDIM + p];
            float dtx = dt * xp;
            f32x4 o = cur[it] * dA + dtx * Bv;
            __builtin_nontemporal_store(o, (f32x4*)(op + (size_t)p * DSTATE + nq));
            f32x4 a4 = o * Cv;
            float acc = (a4[0] + a4[1]) + (a4[2] + a4[3]);
            acc += __shfl_xor(acc, 1);
            acc += __shfl_xor(acc, 2);
            acc += __shfl_xor(acc, 4);
            acc += __shfl_xor(acc, 8);
            if ((t & 15) == 0) yrow[h * HEADDIM + p] = acc + Dk * xp;
        }
        if (h + 1 < NHEADS) {
            #pragma unroll
            for (int it = 0; it < 8; ++it) cur[it] = nxt[it];
        }
    }
    __syncthreads();

    // gate + rmsnorm over HIDDEN (vectorized: 4 consecutive per thread, coalesced)
    const int j0 = t * 4;
    bf16x4 z4 = *(const bf16x4*)(prow + j0);
    f32x4 y4 = *(const f32x4*)&yrow[j0];
    f32x4 vv;
    float ssum = 0.f;
    #pragma unroll
    for (int k = 0; k < 4; ++k) {
        float z = (float)z4[k];
        float val = y4[k] * (z / (1.f + expf(-z)));
        vv[k] = val;
        ssum += val * val;
    }
    float tot = block_sum(ssum, red, t);
    float sc = rsqrtf(tot / (float)HIDDEN + EPS);
    float4 pw4 = *(const float4*)(pw + j0);
    bf16x4 g4 = { (__bf16)(vv[0] * sc * pw4.x), (__bf16)(vv[1] * sc * pw4.y),
                  (__bf16)(vv[2] * sc * pw4.z), (__bf16)(vv[3] * sc * pw4.w) };
    *(bf16x4*)(Gb + (size_t)b * HIDDEN + j0) = g4;
}

// ---------------- launch ----------------
extern "C" void kernel_launch(void* const* d_in, const int* in_sizes, int n_in,
                              void* d_out, int out_size, void* d_ws, size_t ws_size,
                              hipStream_t stream) {
    const float* stoch      = (const float*)d_in[0];
    const float* deter      = (const float*)d_in[1];
    const float* action     = (const float*)d_in[2];
    const float* conv_state = (const float*)d_in[3];
    const float* ssm_state  = (const float*)d_in[4];
    const float* in_proj_w  = (const float*)d_in[5];
    const float* in_proj_b  = (const float*)d_in[6];
    const float* in_norm_w  = (const float*)d_in[7];
    const float* blk_norm_w = (const float*)d_in[8];
    const float* blk_in_w   = (const float*)d_in[9];
    const float* blk_conv_w = (const float*)d_in[10];
    const float* blk_conv_b = (const float*)d_in[11];
    const float* blk_A_log  = (const float*)d_in[12];
    const float* blk_D      = (const float*)d_in[13];
    const float* blk_dt_bias= (const float*)d_in[14];
    const float* blk_post_norm_w = (const float*)d_in[15];
    const float* blk_out_w  = (const float*)d_in[16];
    const float* blk_out_b  = (const float*)d_in[17];
    const float* out_norm_w = (const float*)d_in[18];

    float* out_deter = (float*)d_out;
    float* out_cs    = out_deter + (size_t)B_SZ * DETER;
    float* out_ss    = out_cs + (size_t)2 * B_SZ * CONV_DIM * 3;

    char* ws = (char*)d_ws;
    __bf16* Wb_inproj = (__bf16*)ws;  ws += (size_t)TOKEN_DIM * KIN * 2;
    __bf16* Wb_blkin  = (__bf16*)ws;  ws += (size_t)2 * IPP2 * TOKEN_DIM * 2;
    __bf16* Wb_blkout = (__bf16*)ws;  ws += (size_t)2 * TOKEN_DIM * HIDDEN * 2;
    float*  X         = (float*)ws;   ws += (size_t)B_SZ * TOKEN_DIM * 4;
    __bf16* Hb        = (__bf16*)ws;  ws += (size_t)B_SZ * TOKEN_DIM * 2;
    __bf16* PROJ      = (__bf16*)ws;  ws += (size_t)B_SZ * IPP2 * 2;    // bf16
    __bf16* Gb        = (__bf16*)ws;  ws += (size_t)B_SZ * HIDDEN * 2;
    float*  PART      = (float*)ws;   ws += (size_t)4 * B_SZ * TOKEN_DIM * 4;
    __bf16* INPb = PROJ;   // alias: consumed by input GEMM before PROJ written

    // 0. weights -> bf16 (padded) + input row build (one kernel)
    {
        int total = N0C + N1C + N2C + N3C;
        prep_all<<<(total + 255) / 256, 256, 0, stream>>>(
            in_proj_w, blk_in_w, blk_out_w, stoch, action,
            Wb_inproj, Wb_blkin, Wb_blkout, INPb);
    }
    // 1. input GEMM (split-K 4: 17 steps -> 5,5,5,2) + fused reduce/rms/silu/rms
    {
        dim3 grid(TOKEN_DIM / 64, B_SZ / 128, 4);
        gemm_v2<true, float><<<grid, 256, 0, stream>>>(INPb, Wb_inproj, nullptr, PART,
                                                       B_SZ, TOKEN_DIM, KIN, 5);
        reduce_in_kernel<<<B_SZ, 256, 0, stream>>>(PART, in_proj_b, in_norm_w,
                                                   blk_norm_w, X, Hb);
    }

    for (int l = 0; l < 2; ++l) {
        const __bf16* iw = Wb_blkin + (size_t)l * IPP2 * TOKEN_DIM;
        const float* cw  = blk_conv_w + (size_t)l * CONV_DIM * 4;
        const float* cbv = blk_conv_b + (size_t)l * CONV_DIM;
        const float* alog= blk_A_log + (size_t)l * NHEADS;
        const float* Dvv = blk_D + (size_t)l * NHEADS;
        const float* dtb = blk_dt_bias + (size_t)l * NHEADS;
        const float* pw  = blk_post_norm_w + (size_t)l * HIDDEN;
        const __bf16* ow = Wb_blkout + (size_t)l * TOKEN_DIM * HIDDEN;
        const float* ob  = blk_out_b + (size_t)l * TOKEN_DIM;
        const float* cs_in = conv_state + (size_t)l * B_SZ * CONV_DIM * 3;
        const float* ss_in = ssm_state + (size_t)l * B_SZ * NHEADS * HEADDIM * DSTATE;
        float* cs_out = out_cs + (size_t)l * B_SZ * CONV_DIM * 3;
        float* ss_out = out_ss + (size_t)l * B_SZ * NHEADS * HEADDIM * DSTATE;

        // in-proj GEMM (no split): N=2304, bf16 out
        {
            dim3 grid(IPP2 / 64, B_SZ / 128);
            gemm_v2<false, __bf16><<<grid, 256, 0, stream>>>(Hb, iw, nullptr, PROJ,
                                                             B_SZ, IPP2, TOKEN_DIM, 0);
        }
        // fused conv + ssm + gate-rmsnorm
        conv_ssm_gate_kernel<<<B_SZ, 256, 0, stream>>>(
            cs_in, PROJ, cw, cbv, dtb, alog, Dvv, pw, ss_in, cs_out, ss_out, Gb);
        // out GEMM (split-K 4: 16 steps -> 4 each)
        {
            dim3 grid(TOKEN_DIM / 64, B_SZ / 128, 4);
            gemm_v2<true, float><<<grid, 256, 0, stream>>>(Gb, ow, nullptr, PART,
                                                           B_SZ, TOKEN_DIM, HIDDEN, 4);
        }
        // fused residual + rms (next layer or final tape)
        if (l == 0) {
            reduce_out_kernel<0><<<B_SZ, 256, 0, stream>>>(
                PART, ob, X, blk_norm_w + TOKEN_DIM, X, Hb, nullptr, nullptr);
        } else {
            reduce_out_kernel<1><<<B_SZ, 256, 0, stream>>>(
                PART, ob, X, out_norm_w, nullptr, nullptr, deter, out_deter);
        }
    }
}

// Round 11
// 278.030 us; speedup vs baseline: 1.0710x; 1.0075x over previous
//
#include <hip/hip_runtime.h>
#include <hip/hip_bf16.h>
#include <math.h>

#define B_SZ 1024
#define STOCH 1024
#define ACT 32
#define DETER 4096
#define TOKEN_DIM 512
#define HIDDEN 1024
#define NHEADS 8
#define HEADDIM 128
#define DSTATE 64
#define CONV_DIM 1152
#define IN_PROJ_DIM 2184
#define IPP2 2304         // in_proj N padded to 36*64
#define KIN 1088          // input GEMM K padded to 17*64
#define EPS 0.0001f

typedef float f32x4 __attribute__((ext_vector_type(4)));
typedef __bf16 bf16x8 __attribute__((ext_vector_type(8)));
typedef __bf16 bf16x4 __attribute__((ext_vector_type(4)));

// ---------------- fused prep: weights -> bf16 (padded) + input row build ----------------
#define N0C (512 * KIN / 4)
#define N1C (2 * IPP2 * TOKEN_DIM / 4)
#define N2C (2 * TOKEN_DIM * HIDDEN / 4)
#define N3C (B_SZ * KIN / 4)
__global__ __launch_bounds__(256) void prep_all(
    const float* __restrict__ inproj, const float* __restrict__ blkin,
    const float* __restrict__ blkout,
    const float* __restrict__ stoch, const float* __restrict__ action,
    __bf16* __restrict__ w0, __bf16* __restrict__ w1, __bf16* __restrict__ w2,
    __bf16* __restrict__ inp)
{
    int i = blockIdx.x * 256 + threadIdx.x;
    bf16x4 o = { (__bf16)0.f, (__bf16)0.f, (__bf16)0.f, (__bf16)0.f };
    if (i < N0C) {
        int idx = i * 4;
        int rr = idx / KIN, cc = idx % KIN;
        if (cc < STOCH + ACT) {
            float4 v = *(const float4*)(inproj + (size_t)rr * (STOCH + ACT) + cc);
            o = bf16x4{ (__bf16)v.x, (__bf16)v.y, (__bf16)v.z, (__bf16)v.w };
        }
        ((bf16x4*)w0)[i] = o;
    } else if (i < N0C + N1C) {
        int j = i - N0C;
        int idx = j * 4;
        int li  = idx / (IPP2 * TOKEN_DIM);
        int rem = idx % (IPP2 * TOKEN_DIM);
        int rr  = rem / TOKEN_DIM, cc = rem % TOKEN_DIM;
        if (rr < IN_PROJ_DIM) {
            float4 v = *(const float4*)(blkin + ((size_t)li * IN_PROJ_DIM + rr) * TOKEN_DIM + cc);
            o = bf16x4{ (__bf16)v.x, (__bf16)v.y, (__bf16)v.z, (__bf16)v.w };
        }
        ((bf16x4*)w1)[j] = o;
    } else if (i < N0C + N1C + N2C) {
        int j = i - N0C - N1C;
        float4 v = ((const float4*)blkout)[j];
        o = bf16x4{ (__bf16)v.x, (__bf16)v.y, (__bf16)v.z, (__bf16)v.w };
        ((bf16x4*)w2)[j] = o;
    } else if (i < N0C + N1C + N2C + N3C) {
        int j = i - N0C - N1C - N2C;
        int idx = j * 4;
        int b = idx / KIN, c = idx % KIN;
        if (c < STOCH) {
            float4 v = *(const float4*)(stoch + (size_t)b * STOCH + c);
            o = bf16x4{ (__bf16)v.x, (__bf16)v.y, (__bf16)v.z, (__bf16)v.w };
        } else if (c < STOCH + ACT) {
            float4 v = *(const float4*)(action + (size_t)b * ACT + (c - STOCH));
            float4 m;
            m.x = fabsf(v.x) > 1.f ? fabsf(v.x) : 1.f;
            m.y = fabsf(v.y) > 1.f ? fabsf(v.y) : 1.f;
            m.z = fabsf(v.z) > 1.f ? fabsf(v.z) : 1.f;
            m.w = fabsf(v.w) > 1.f ? fabsf(v.w) : 1.f;
            o = bf16x4{ (__bf16)(v.x / m.x), (__bf16)(v.y / m.y),
                        (__bf16)(v.z / m.z), (__bf16)(v.w / m.w) };
        }
        ((bf16x4*)inp)[j] = o;
    }
}

// ---------------- GEMM v2: 128x64 wg tile, wave 32x64, optional split-K ----------
// C = A_bf16(MxK) @ W_bf16(NxK)^T   M%128==0, N%64==0, K%64==0
template<bool SPLIT, typename OutT>
__global__ __launch_bounds__(256) void gemm_v2(
    const __bf16* __restrict__ A,
    const __bf16* __restrict__ W,
    const float* __restrict__ bias,   // only used when !SPLIT (may be null)
    OutT* __restrict__ C,             // !SPLIT: MxN ; SPLIT: [z][M][N]
    int M, int N, int K, int chunk_steps)
{
    __shared__ __bf16 As[128 * 64];   // 128 rows x 128B, XOR-swizzled
    __shared__ __bf16 Ws[64 * 64];
    const int tid = threadIdx.x;
    const int bn = blockIdx.x * 64;
    const int bm = blockIdx.y * 128;
    const int nsteps = K >> 6;
    int s_begin = 0, s_end = nsteps;
    OutT* Cout = C;
    if (SPLIT) {
        int z = blockIdx.z;
        s_begin = z * chunk_steps;
        int se = s_begin + chunk_steps;
        s_end = se < nsteps ? se : nsteps;
        Cout = C + (size_t)z * M * N;
    }

    const int wid = tid >> 6;
    const int lane = tid & 63;
    const int wr = wid * 32;
    const int r = lane & 15;
    const int kb = (lane >> 4) * 16;

    const int row0 = tid >> 3;
    const int colb = (tid & 7) * 16;
    const int wof = row0 * 128 + (colb ^ ((row0 & 7) << 4));
    char* Asb = (char*)As;
    char* Wsb = (char*)Ws;

    const __bf16* gA = A + (size_t)(bm + row0) * K + (s_begin << 6) + (colb >> 1);
    const __bf16* gW = W + (size_t)(bn + row0) * K + (s_begin << 6) + (colb >> 1);
    const size_t aK32 = (size_t)32 * K;

    const int ar0 = wr + r;
    const int ar1 = wr + 16 + r;
    const int aswz = (ar0 & 7) << 4;
    const int bswz = (r & 7) << 4;

    f32x4 acc[2][4] = {};
    bf16x8 va0 = *(const bf16x8*)(gA);
    bf16x8 va1 = *(const bf16x8*)(gA + aK32);
    bf16x8 va2 = *(const bf16x8*)(gA + 2 * aK32);
    bf16x8 va3 = *(const bf16x8*)(gA + 3 * aK32);
    bf16x8 vw0 = *(const bf16x8*)(gW);
    bf16x8 vw1 = *(const bf16x8*)(gW + aK32);

    for (int s = s_begin; s < s_end; ++s) {
        __syncthreads();
        *(bf16x8*)(Asb + wof) = va0;
        *(bf16x8*)(Asb + wof + 32 * 128) = va1;
        *(bf16x8*)(Asb + wof + 64 * 128) = va2;
        *(bf16x8*)(Asb + wof + 96 * 128) = va3;
        *(bf16x8*)(Wsb + wof) = vw0;
        *(bf16x8*)(Wsb + wof + 32 * 128) = vw1;
        __syncthreads();
        if (s + 1 < s_end) {
            const int ko = (s + 1 - s_begin) << 6;
            va0 = *(const bf16x8*)(gA + ko);
            va1 = *(const bf16x8*)(gA + aK32 + ko);
            va2 = *(const bf16x8*)(gA + 2 * aK32 + ko);
            va3 = *(const bf16x8*)(gA + 3 * aK32 + ko);
            vw0 = *(const bf16x8*)(gW + ko);
            vw1 = *(const bf16x8*)(gW + aK32 + ko);
        }
        #pragma unroll
        for (int ks = 0; ks < 2; ++ks) {
            const int cb = ks * 64 + kb;
            bf16x8 a0 = *(const bf16x8*)(Asb + ar0 * 128 + (cb ^ aswz));
            bf16x8 a1 = *(const bf16x8*)(Asb + ar1 * 128 + (cb ^ aswz));
            bf16x8 b0 = *(const bf16x8*)(Wsb + r * 128 + (cb ^ bswz));
            bf16x8 b1 = *(const bf16x8*)(Wsb + (r + 16) * 128 + (cb ^ bswz));
            bf16x8 b2 = *(const bf16x8*)(Wsb + (r + 32) * 128 + (cb ^ bswz));
            bf16x8 b3 = *(const bf16x8*)(Wsb + (r + 48) * 128 + (cb ^ bswz));
            acc[0][0] = __builtin_amdgcn_mfma_f32_16x16x32_bf16(a0, b0, acc[0][0], 0, 0, 0);
            acc[0][1] = __builtin_amdgcn_mfma_f32_16x16x32_bf16(a0, b1, acc[0][1], 0, 0, 0);
            acc[0][2] = __builtin_amdgcn_mfma_f32_16x16x32_bf16(a0, b2, acc[0][2], 0, 0, 0);
            acc[0][3] = __builtin_amdgcn_mfma_f32_16x16x32_bf16(a0, b3, acc[0][3], 0, 0, 0);
            acc[1][0] = __builtin_amdgcn_mfma_f32_16x16x32_bf16(a1, b0, acc[1][0], 0, 0, 0);
            acc[1][1] = __builtin_amdgcn_mfma_f32_16x16x32_bf16(a1, b1, acc[1][1], 0, 0, 0);
            acc[1][2] = __builtin_amdgcn_mfma_f32_16x16x32_bf16(a1, b2, acc[1][2], 0, 0, 0);
            acc[1][3] = __builtin_amdgcn_mfma_f32_16x16x32_bf16(a1, b3, acc[1][3], 0, 0, 0);
        }
    }

    const int cr = (lane >> 4) * 4;
    const int cc = lane & 15;
    #pragma unroll
    for (int mi = 0; mi < 2; mi++) {
        #pragma unroll
        for (int ni = 0; ni < 4; ni++) {
            int n = bn + ni * 16 + cc;
            #pragma unroll
            for (int j = 0; j < 4; j++) {
                int m = bm + wr + mi * 16 + cr + j;
                float v = acc[mi][ni][j];
                if (!SPLIT && bias) v += bias[n];
                Cout[(size_t)m * N + n] = (OutT)v;
            }
        }
    }
}

// ---------------- block-wide sum helper (256 threads) ----------------
__device__ __forceinline__ float block_sum(float v, float* red, int t) {
    #pragma unroll
    for (int off = 32; off >= 1; off >>= 1) v += __shfl_xor(v, off);
    if ((t & 63) == 0) red[t >> 6] = v;
    __syncthreads();
    float tot = red[0] + red[1] + red[2] + red[3];
    __syncthreads();
    return tot;
}

// ---------------- reduce_in: X = silu(rmsnorm(ΣP+bias, inw)); Hb = bf16(rmsnorm(X, nw)) ----
template<int NP>
__global__ __launch_bounds__(256) void reduce_in_kernel(
    const __bf16* __restrict__ P,     // [NP][B][512] bf16 partials
    const float* __restrict__ bias,
    const float* __restrict__ inw,
    const float* __restrict__ nw,
    float* __restrict__ X, __bf16* __restrict__ Hb)
{
    __shared__ float red[4];
    int b = blockIdx.x, t = threadIdx.x;
    const size_t stride = (size_t)B_SZ * TOKEN_DIM;
    float h[2];
    float ss = 0.f;
    #pragma unroll
    for (int i = 0; i < 2; i++) {
        int c = t + i * 256;
        size_t o = (size_t)b * TOKEN_DIM + c;
        float v = bias[c];
        #pragma unroll
        for (int k = 0; k < NP; ++k) v += (float)P[o + k * stride];
        h[i] = v;
        ss += v * v;
    }
    float tot = block_sum(ss, red, t);
    float sc = rsqrtf(tot / (float)TOKEN_DIM + EPS);
    float ss2 = 0.f;
    #pragma unroll
    for (int i = 0; i < 2; i++) {
        int c = t + i * 256;
        float v = h[i] * sc * inw[c];
        v = v / (1.f + expf(-v));        // silu
        h[i] = v;
        X[(size_t)b * TOKEN_DIM + c] = v;
        ss2 += v * v;
    }
    float tot2 = block_sum(ss2, red, t);
    float sc2 = rsqrtf(tot2 / (float)TOKEN_DIM + EPS);
    #pragma unroll
    for (int i = 0; i < 2; i++) {
        int c = t + i * 256;
        Hb[(size_t)b * TOKEN_DIM + c] = (__bf16)(h[i] * sc2 * nw[c]);
    }
}

// ---------------- reduce_out: newX = X + ΣP + ob; MODE0: X,Hb=rms(newX,w); MODE1: final tape ----
template<int MODE, int NP>
__global__ __launch_bounds__(256) void reduce_out_kernel(
    const __bf16* __restrict__ P,     // [NP][B][512] bf16 partials
    const float* __restrict__ ob,
    const float* __restrict__ Xin,
    const float* __restrict__ w,
    float* __restrict__ X,
    __bf16* __restrict__ Hb,
    const float* __restrict__ deter,
    float* __restrict__ out)
{
    __shared__ float red[4];
    int b = blockIdx.x, t = threadIdx.x;
    const size_t stride = (size_t)B_SZ * TOKEN_DIM;
    float h[2];
    float ss = 0.f;
    #pragma unroll
    for (int i = 0; i < 2; i++) {
        int c = t + i * 256;
        size_t o = (size_t)b * TOKEN_DIM + c;
        float v = Xin[o] + ob[c];
        #pragma unroll
        for (int k = 0; k < NP; ++k) v += (float)P[o + k * stride];
        h[i] = v;
        ss += v * v;
    }
    float tot = block_sum(ss, red, t);
    float sc = rsqrtf(tot / (float)TOKEN_DIM + EPS);
    if (MODE == 0) {
        #pragma unroll
        for (int i = 0; i < 2; i++) {
            int c = t + i * 256;
            size_t o = (size_t)b * TOKEN_DIM + c;
            X[o] = h[i];
            Hb[o] = (__bf16)(h[i] * sc * w[c]);
        }
    } else {
        #pragma unroll
        for (int i = 0; i < 2; i++) {
            int c = t + i * 256;
            out[(size_t)b * DETER + 3584 + c] = h[i] * sc * w[c];
        }
        const float4* src = (const float4*)(deter + (size_t)b * DETER + TOKEN_DIM);
        float4* dst = (float4*)(out + (size_t)b * DETER);
        #pragma unroll
        for (int j = 0; j < 4; ++j) {
            int idx = t + j * 256;
            if (idx < 896) dst[idx] = src[idx];
        }
    }
}

// ---------------- fused conv + ssm + gate-rmsnorm (one block per batch row) ----------------
// r10 structure: strided coalesced conv phase, head-pipelined SSM, vectorized gate.
__global__ __launch_bounds__(256, 4) void conv_ssm_gate_kernel(
    const float* __restrict__ cs,      // B x CONV_DIM x 3
    const __bf16* __restrict__ proj,   // B x IPP2 (bf16)
    const float* __restrict__ cw,      // CONV_DIM x 4
    const float* __restrict__ cb,      // CONV_DIM
    const float* __restrict__ dtb,     // NHEADS
    const float* __restrict__ alog,    // NHEADS
    const float* __restrict__ Dv,      // NHEADS
    const float* __restrict__ pw,      // HIDDEN
    const float* __restrict__ ss,      // B x NHEADS x HEADDIM x DSTATE
    float* __restrict__ new_cs,
    float* __restrict__ new_ss,
    __bf16* __restrict__ Gb)           // B x HIDDEN
{
    __shared__ float convs[CONV_DIM];  // x(1024) | B(64) | C(64)
    __shared__ float yrow[HIDDEN];
    __shared__ float dts[NHEADS], dAs[NHEADS], dvs[NHEADS];
    __shared__ float red[4];

    int b = blockIdx.x, t = threadIdx.x;
    const __bf16* prow = proj + (size_t)b * IPP2;

    const int p0 = t >> 4;            // 0..15
    const int nq = (t & 15) * 4;      // 0..60
    const float* basep = ss + (size_t)b * NHEADS * HEADDIM * DSTATE;
    float* baseo = new_ss + (size_t)b * NHEADS * HEADDIM * DSTATE;

    // prefetch head 0 state (in flight during conv phase)
    f32x4 cur[8], nxt[8];
    #pragma unroll
    for (int it = 0; it < 8; ++it) {
        int p = it * 16 + p0;
        cur[it] = __builtin_nontemporal_load((const f32x4*)(basep + (size_t)p * DSTATE + nq));
    }

    if (t < NHEADS) {
        float dtr = (float)prow[HIDDEN + CONV_DIM + t] + dtb[t];
        float dt = dtr > 20.f ? dtr : log1pf(expf(dtr));
        dts[t] = dt;
        dAs[t] = expf(dt * -expf(alog[t]));
        dvs[t] = Dv[t];
    }
    // conv over 1152 channels (strided per-lane: per-instruction coalesced)
    for (int c = t; c < CONV_DIM; c += 256) {
        const float* s = cs + ((size_t)b * CONV_DIM + c) * 3;
        float s0 = s[0], s1 = s[1], s2 = s[2];
        float xbc = (float)prow[HIDDEN + c];
        float4 wv = *(const float4*)(cw + c * 4);
        float v = wv.x * s0 + wv.y * s1 + wv.z * s2 + wv.w * xbc + cb[c];
        v = v / (1.f + expf(-v));
        convs[c] = v;
        float* nc = new_cs + ((size_t)b * CONV_DIM + c) * 3;
        nc[0] = s1; nc[1] = s2; nc[2] = xbc;
    }
    __syncthreads();

    const f32x4 Bv = *(const f32x4*)&convs[HIDDEN + nq];
    const f32x4 Cv = *(const f32x4*)&convs[HIDDEN + DSTATE + nq];

    #pragma unroll
    for (int h = 0; h < NHEADS; ++h) {
        if (h + 1 < NHEADS) {
            #pragma unroll
            for (int it = 0; it < 8; ++it) {
                int p = it * 16 + p0;
                nxt[it] = __builtin_nontemporal_load(
                    (const f32x4*)(basep + (size_t)((h + 1) * HEADDIM + p) * DSTATE + nq));
            }
        }
        const float dt = dts[h], dA = dAs[h], Dk = dvs[h];
        float* op = baseo + (size_t)h * HEADDIM * DSTATE;
        #pragma unroll
        for (int it = 0; it < 8; ++it) {
            int p = it * 16 + p0;
            float xp = convs[h * HEADDIM + p];
            float dtx = dt * xp;
            f32x4 o = cur[it] * dA + dtx * Bv;
            __builtin_nontemporal_store(o, (f32x4*)(op + (size_t)p * DSTATE + nq));
            f32x4 a4 = o * Cv;
            float acc = (a4[0] + a4[1]) + (a4[2] + a4[3]);
            acc += __shfl_xor(acc, 1);
            acc += __shfl_xor(acc, 2);
            acc += __shfl_xor(acc, 4);
            acc += __shfl_xor(acc, 8);
            if ((t & 15) == 0) yrow[h * HEADDIM + p] = acc + Dk * xp;
        }
        if (h + 1 < NHEADS) {
            #pragma unroll
            for (int it = 0; it < 8; ++it) cur[it] = nxt[it];
        }
    }
    __syncthreads();

    // gate + rmsnorm over HIDDEN (vectorized: 4 consecutive per thread, coalesced)
    const int j0 = t * 4;
    bf16x4 z4 = *(const bf16x4*)(prow + j0);
    f32x4 y4 = *(const f32x4*)&yrow[j0];
    f32x4 vv;
    float ssum = 0.f;
    #pragma unroll
    for (int k = 0; k < 4; ++k) {
        float z = (float)z4[k];
        float val = y4[k] * (z / (1.f + expf(-z)));
        vv[k] = val;
        ssum += val * val;
    }
    float tot = block_sum(ssum, red, t);
    float sc = rsqrtf(tot / (float)HIDDEN + EPS);
    float4 pw4 = *(const float4*)(pw + j0);
    bf16x4 g4 = { (__bf16)(vv[0] * sc * pw4.x), (__bf16)(vv[1] * sc * pw4.y),
                  (__bf16)(vv[2] * sc * pw4.z), (__bf16)(vv[3] * sc * pw4.w) };
    *(bf16x4*)(Gb + (size_t)b * HIDDEN + j0) = g4;
}

// ---------------- launch ----------------
extern "C" void kernel_launch(void* const* d_in, const int* in_sizes, int n_in,
                              void* d_out, int out_size, void* d_ws, size_t ws_size,
                              hipStream_t stream) {
    const float* stoch      = (const float*)d_in[0];
    const float* deter      = (const float*)d_in[1];
    const float* action     = (const float*)d_in[2];
    const float* conv_state = (const float*)d_in[3];
    const float* ssm_state  = (const float*)d_in[4];
    const float* in_proj_w  = (const float*)d_in[5];
    const float* in_proj_b  = (const float*)d_in[6];
    const float* in_norm_w  = (const float*)d_in[7];
    const float* blk_norm_w = (const float*)d_in[8];
    const float* blk_in_w   = (const float*)d_in[9];
    const float* blk_conv_w = (const float*)d_in[10];
    const float* blk_conv_b = (const float*)d_in[11];
    const float* blk_A_log  = (const float*)d_in[12];
    const float* blk_D      = (const float*)d_in[13];
    const float* blk_dt_bias= (const float*)d_in[14];
    const float* blk_post_norm_w = (const float*)d_in[15];
    const float* blk_out_w  = (const float*)d_in[16];
    const float* blk_out_b  = (const float*)d_in[17];
    const float* out_norm_w = (const float*)d_in[18];

    float* out_deter = (float*)d_out;
    float* out_cs    = out_deter + (size_t)B_SZ * DETER;
    float* out_ss    = out_cs + (size_t)2 * B_SZ * CONV_DIM * 3;

    char* ws = (char*)d_ws;
    __bf16* Wb_inproj = (__bf16*)ws;  ws += (size_t)TOKEN_DIM * KIN * 2;
    __bf16* Wb_blkin  = (__bf16*)ws;  ws += (size_t)2 * IPP2 * TOKEN_DIM * 2;
    __bf16* Wb_blkout = (__bf16*)ws;  ws += (size_t)2 * TOKEN_DIM * HIDDEN * 2;
    float*  X         = (float*)ws;   ws += (size_t)B_SZ * TOKEN_DIM * 4;
    __bf16* Hb        = (__bf16*)ws;  ws += (size_t)B_SZ * TOKEN_DIM * 2;
    __bf16* PROJ      = (__bf16*)ws;  ws += (size_t)B_SZ * IPP2 * 2;    // bf16
    __bf16* Gb        = (__bf16*)ws;  ws += (size_t)B_SZ * HIDDEN * 2;
    __bf16* PART      = (__bf16*)ws;  ws += (size_t)8 * B_SZ * TOKEN_DIM * 2;  // bf16 partials
    __bf16* INPb = PROJ;   // alias: consumed by input GEMM before PROJ written

    // 0. weights -> bf16 (padded) + input row build (one kernel)
    {
        int total = N0C + N1C + N2C + N3C;
        prep_all<<<(total + 255) / 256, 256, 0, stream>>>(
            in_proj_w, blk_in_w, blk_out_w, stoch, action,
            Wb_inproj, Wb_blkin, Wb_blkout, INPb);
    }
    // 1. input GEMM (split-K 6: 17 steps -> 3,3,3,3,3,2) + fused reduce/rms/silu/rms
    {
        dim3 grid(TOKEN_DIM / 64, B_SZ / 128, 6);
        gemm_v2<true, __bf16><<<grid, 256, 0, stream>>>(INPb, Wb_inproj, nullptr, PART,
                                                        B_SZ, TOKEN_DIM, KIN, 3);
        reduce_in_kernel<6><<<B_SZ, 256, 0, stream>>>(PART, in_proj_b, in_norm_w,
                                                      blk_norm_w, X, Hb);
    }

    for (int l = 0; l < 2; ++l) {
        const __bf16* iw = Wb_blkin + (size_t)l * IPP2 * TOKEN_DIM;
        const float* cw  = blk_conv_w + (size_t)l * CONV_DIM * 4;
        const float* cbv = blk_conv_b + (size_t)l * CONV_DIM;
        const float* alog= blk_A_log + (size_t)l * NHEADS;
        const float* Dvv = blk_D + (size_t)l * NHEADS;
        const float* dtb = blk_dt_bias + (size_t)l * NHEADS;
        const float* pw  = blk_post_norm_w + (size_t)l * HIDDEN;
        const __bf16* ow = Wb_blkout + (size_t)l * TOKEN_DIM * HIDDEN;
        const float* ob  = blk_out_b + (size_t)l * TOKEN_DIM;
        const float* cs_in = conv_state + (size_t)l * B_SZ * CONV_DIM * 3;
        const float* ss_in = ssm_state + (size_t)l * B_SZ * NHEADS * HEADDIM * DSTATE;
        float* cs_out = out_cs + (size_t)l * B_SZ * CONV_DIM * 3;
        float* ss_out = out_ss + (size_t)l * B_SZ * NHEADS * HEADDIM * DSTATE;

        // in-proj GEMM (no split): N=2304, bf16 out
        {
            dim3 grid(IPP2 / 64, B_SZ / 128);
            gemm_v2<false, __bf16><<<grid, 256, 0, stream>>>(Hb, iw, nullptr, PROJ,
                                                             B_SZ, IPP2, TOKEN_DIM, 0);
        }
        // fused conv + ssm + gate-rmsnorm
        conv_ssm_gate_kernel<<<B_SZ, 256, 0, stream>>>(
            cs_in, PROJ, cw, cbv, dtb, alog, Dvv, pw, ss_in, cs_out, ss_out, Gb);
        // out GEMM (split-K 8: 16 steps -> 2 each)
        {
            dim3 grid(TOKEN_DIM / 64, B_SZ / 128, 8);
            gemm_v2<true, __bf16><<<grid, 256, 0, stream>>>(Gb, ow, nullptr, PART,
                                                            B_SZ, TOKEN_DIM, HIDDEN, 2);
        }
        // fused residual + rms (next layer or final tape)
        if (l == 0) {
            reduce_out_kernel<0, 8><<<B_SZ, 256, 0, stream>>>(
                PART, ob, X, blk_norm_w + TOKEN_DIM, X, Hb, nullptr, nullptr);
        } else {
            reduce_out_kernel<1, 8><<<B_SZ, 256, 0, stream>>>(
                PART, ob, X, out_norm_w, nullptr, nullptr, deter, out_deter);
        }
    }
}